// Round 4
// baseline (1618.629 us; speedup 1.0000x reference)
//
#include <hip/hip_runtime.h>

#define HW   36864      // 192*192
#define NPOS 73728      // B*HW, B=2
#define EPSV 1e-5f

// channel-slot layout in workspace (each slot = NPOS floats)
#define S1_HF1  0
#define S1_FD1  20
#define S1_PHU1 50
#define S1_PHL1 70
#define S1_HD1  90
#define S2_HF2  160
#define S2_FD2  170
#define S2_PHU2 200
#define S2_PHL2 210
#define S2_HD2  220
#define S3_FU   0       // reuse stage-1 slots (dead by stage 3)
#define S3_HU   20
#define S3_PU   50
#define ST3_FU  290     // stat-channel bases for stage 3
#define ST3_HU  310
#define ST3_PU  340
#define NSLOT 290
#define NSTAT 410
#define L2OFF 160       // stage-2 stat range starts at 160

#define MT 10           // output channels per block (COUT slice)

__device__ __forceinline__ float4 ld4(const float* p) { return *(const float4*)p; }

__device__ __forceinline__ float4 bnrelu4(float4 v, float sc, float sh) {
    float4 r;
    r.x = fmaf(v.x, sc, sh); r.y = fmaf(v.y, sc, sh);
    r.z = fmaf(v.z, sc, sh); r.w = fmaf(v.w, sc, sh);
    r.x = r.x > 0.f ? r.x : 0.f;
    r.y = r.y > 0.f ? r.y : 0.f;
    r.z = r.z > 0.f ? r.z : 0.f;
    r.w = r.w > 0.f ? r.w : 0.f;
    return r;
}

// ---------------------------------------------------------------------------
// Stage this block's MT-row weight slice into LDS, rows padded to CINP floats
// (multiple of 4) so weight reads are broadcast ds_read_b128 (conflict-free).
// ---------------------------------------------------------------------------
template<int CIN, int CINP>
__device__ __forceinline__ void stage_w(const float* __restrict__ w, float* wl)
{
    if (CIN == CINP) {
        for (int idx = threadIdx.x; idx < MT * CIN; idx += 256)
            wl[idx] = w[idx];
    } else {
        for (int idx = threadIdx.x; idx < MT * CIN; idx += 256) {
            int o = idx / CIN;
            int c = idx - o * CIN;
            wl[o * CINP + c] = w[idx];
        }
    }
    __syncthreads();
}

// 4 channels x 4 positions for one output channel: 16 fmaf, channel-ascending
__device__ __forceinline__ void fma4x4(float4& a, float4 w, const float4* buf)
{
    a.x = fmaf(w.x, buf[0].x, a.x); a.y = fmaf(w.x, buf[0].y, a.y);
    a.z = fmaf(w.x, buf[0].z, a.z); a.w = fmaf(w.x, buf[0].w, a.w);
    a.x = fmaf(w.y, buf[1].x, a.x); a.y = fmaf(w.y, buf[1].y, a.y);
    a.z = fmaf(w.y, buf[1].z, a.z); a.w = fmaf(w.y, buf[1].w, a.w);
    a.x = fmaf(w.z, buf[2].x, a.x); a.y = fmaf(w.z, buf[2].y, a.y);
    a.z = fmaf(w.z, buf[2].z, a.z); a.w = fmaf(w.z, buf[2].w, a.w);
    a.x = fmaf(w.w, buf[3].x, a.x); a.y = fmaf(w.w, buf[3].y, a.y);
    a.z = fmaf(w.w, buf[3].z, a.z); a.w = fmaf(w.w, buf[3].w, a.w);
}

// one 8-channel chunk for all MT outputs (channels ascending)
template<int CINP>
__device__ __forceinline__ void fma_chunk(float4* acc, const float* wb,
                                          const float4* buf)
{
#pragma unroll
    for (int o = 0; o < MT; ++o) {
        float4 w0 = ld4(wb + o * CINP);
        float4 w1 = ld4(wb + o * CINP + 4);
        fma4x4(acc[o], w0, buf);
        fma4x4(acc[o], w1, buf + 4);
    }
}

// ---------------------------------------------------------------------------
// Register-tiled conv slice: each thread owns FOUR positions (float4), block
// computes MT=10 output channels. Manual ping-pong double buffer (bufA/bufB):
// while the FMA block for chunk k (bufA) runs, only chunk k+1's loads (bufB)
// are outstanding -> compiler emits counted vmcnt waits, loads stay in flight
// across the whole 320-fmaf block. Requires launch_bounds(256,3) so the
// ~145-VGPR live set is not clamped (round-3 failure: 88-VGPR cap sank the
// prefetch back to vmcnt(0)-per-chunk).
// Per-position accumulation order is channel-ascending (matches reference).
// ---------------------------------------------------------------------------
template<int CIN, int CINP, class F>
__device__ __forceinline__ void conv4(F fetch, const float* wl,
                                      float* __restrict__ y, int p,
                                      float* __restrict__ sumA,
                                      float* __restrict__ sumqA,
                                      int stat0, float* red)
{
    float4 acc[MT];
#pragma unroll
    for (int o = 0; o < MT; ++o) acc[o] = make_float4(0.f, 0.f, 0.f, 0.f);

    constexpr int CHUNK = 8;
    constexpr int NCH  = CIN / CHUNK;      // >= 2 for all our CINs
    constexpr int MAIN = NCH * CHUNK;
    static_assert(NCH >= 2, "conv4 requires at least 2 chunks");

    float4 bufA[CHUNK], bufB[CHUNK];
#pragma unroll
    for (int i = 0; i < CHUNK; ++i) bufA[i] = fetch(i);
#pragma unroll
    for (int i = 0; i < CHUNK; ++i) bufB[i] = fetch(CHUNK + i);

#pragma unroll 1
    for (int k = 0; k + 3 < NCH; k += 2) {
        fma_chunk<CINP>(acc, wl + k * CHUNK, bufA);            // consume A
#pragma unroll
        for (int i = 0; i < CHUNK; ++i) bufA[i] = fetch((k + 2) * CHUNK + i);
        fma_chunk<CINP>(acc, wl + (k + 1) * CHUNK, bufB);      // consume B
#pragma unroll
        for (int i = 0; i < CHUNK; ++i) bufB[i] = fetch((k + 3) * CHUNK + i);
    }
    // epilogue: remaining chunks (parity of NCH is compile-time)
    constexpr int KE = (NCH % 2 == 0) ? NCH - 2 : NCH - 3;
    if constexpr (NCH % 2 == 0) {          // 2 chunks left: KE(A), KE+1(B)
        fma_chunk<CINP>(acc, wl + KE * CHUNK, bufA);
        fma_chunk<CINP>(acc, wl + (KE + 1) * CHUNK, bufB);
    } else {                               // 3 left: KE(A), KE+1(B), KE+2(A)
        fma_chunk<CINP>(acc, wl + KE * CHUNK, bufA);
#pragma unroll
        for (int i = 0; i < CHUNK; ++i) bufA[i] = fetch((KE + 2) * CHUNK + i);
        fma_chunk<CINP>(acc, wl + (KE + 1) * CHUNK, bufB);
        fma_chunk<CINP>(acc, wl + (KE + 2) * CHUNK, bufA);
    }

    constexpr int REM = CIN - MAIN;
    int ct = MAIN;
    if (REM >= 4) {                                   // vector tail (4 channels)
        float4 buf4[4];
#pragma unroll
        for (int i = 0; i < 4; ++i) buf4[i] = fetch(ct + i);
#pragma unroll
        for (int o = 0; o < MT; ++o)
            fma4x4(acc[o], ld4(wl + ct + o * CINP), buf4);
        ct += 4;
    }
#pragma unroll
    for (int c = ct; c < CIN; ++c) {                  // scalar tail
        float4 x = fetch(c);
#pragma unroll
        for (int o = 0; o < MT; ++o) {
            float wv = wl[o * CINP + c];
            acc[o].x = fmaf(wv, x.x, acc[o].x);
            acc[o].y = fmaf(wv, x.y, acc[o].y);
            acc[o].z = fmaf(wv, x.z, acc[o].z);
            acc[o].w = fmaf(wv, x.w, acc[o].w);
        }
    }

#pragma unroll
    for (int o = 0; o < MT; ++o)
        *(float4*)(y + (size_t)o * NPOS + p) = acc[o];

    int lane = threadIdx.x & 63;
    int wv_  = threadIdx.x >> 6;
#pragma unroll
    for (int o = 0; o < MT; ++o) {
        float s = (acc[o].x + acc[o].y) + (acc[o].z + acc[o].w);
        float q = (acc[o].x * acc[o].x + acc[o].y * acc[o].y)
                + (acc[o].z * acc[o].z + acc[o].w * acc[o].w);
#pragma unroll
        for (int i = 1; i < 64; i <<= 1) {
            s += __shfl_xor(s, i, 64);
            q += __shfl_xor(q, i, 64);
        }
        if (lane == 0) {
            red[(wv_ * MT + o) * 2]     = s;
            red[(wv_ * MT + o) * 2 + 1] = q;
        }
    }
    __syncthreads();
    if (threadIdx.x < MT) {
        int o = threadIdx.x;
        float s = 0.f, q = 0.f;
#pragma unroll
        for (int k = 0; k < 4; ++k) {
            s += red[(k * MT + o) * 2];
            q += red[(k * MT + o) * 2 + 1];
        }
        atomicAdd(&sumA[stat0 + o], s);
        atomicAdd(&sumqA[stat0 + o], q);
    }
}

// ---------------------------------------------------------------------------
// Stage 1 (heavy-first y-order): hd1(0..6), fd1(7..9), hf1(10,11),
//                                phu1(12,13), phl1(14,15)
// ---------------------------------------------------------------------------
__global__ void __launch_bounds__(256, 3) stage1_kernel(
    const float* __restrict__ xp, const float* __restrict__ xh,
    const float* __restrict__ xf, const float* __restrict__ p_fea,
    const float* __restrict__ h_fea,
    const float* __restrict__ w_hf1, const float* __restrict__ w_fd1,
    const float* __restrict__ w_phu1, const float* __restrict__ w_phl1,
    const float* __restrict__ w_hd1, float* __restrict__ ws)
{
    __shared__ __align__(16) float wlds[MT * 276];
    __shared__ float red[4 * MT * 2];
    int g = blockIdx.x * 256 + threadIdx.x;
    int p = g * 4;
    int b = (p >= HW) ? 1 : 0;
    int s = p - b * HW;
    float* y     = ws;
    float* sumA  = ws + (size_t)NSLOT * NPOS;
    float* sumqA = sumA + NSTAT;
    int yb = blockIdx.y;

    if (yb < 7) {            // hd1: [p_fea; xh1; xh2] (276) -> 7 x 10
        int off = yb * MT;
        stage_w<276, 276>(w_hd1 + off * 276, wlds);
        const float* pb = p_fea + (size_t)b * 256 * HW + s;
        const float* xb = xh + ((size_t)b * 30 + 10) * HW + s;
        conv4<276, 276>([&](int c) { return (c < 256) ? ld4(pb + c * HW)
                                                      : ld4(xb + (c - 256) * HW); },
                        wlds, y + (size_t)(S1_HD1 + off) * NPOS, p,
                        sumA, sumqA, S1_HD1 + off, red);
    } else if (yb < 10) {    // fd1: [h_fea; xf1] (266) -> 3 x 10
        int off = (yb - 7) * MT;
        stage_w<266, 268>(w_fd1 + off * 266, wlds);
        const float* hb  = h_fea + (size_t)b * 256 * HW + s;
        const float* xf1 = xf + ((size_t)b * 20 + 10) * HW + s;
        conv4<266, 268>([&](int c) { return (c < 256) ? ld4(hb + c * HW)
                                                      : ld4(xf1 + (c - 256) * HW); },
                        wlds, y + (size_t)(S1_FD1 + off) * NPOS, p,
                        sumA, sumqA, S1_FD1 + off, red);
    } else if (yb < 12) {    // hf1: [xh1; xh2] (20) -> 10+10
        int off = (yb - 10) * MT;
        stage_w<20, 20>(w_hf1 + off * 20, wlds);
        const float* xb = xh + ((size_t)b * 30 + 10) * HW + s;
        conv4<20, 20>([&](int c) { return ld4(xb + c * HW); },
                      wlds, y + (size_t)(S1_HF1 + off) * NPOS, p,
                      sumA, sumqA, S1_HF1 + off, red);
    } else if (yb < 14) {    // phu1: xp[1:5] (40) -> 10+10
        int off = (yb - 12) * MT;
        stage_w<40, 40>(w_phu1 + off * 40, wlds);
        const float* xb = xp + ((size_t)b * 70 + 10) * HW + s;
        conv4<40, 40>([&](int c) { return ld4(xb + c * HW); },
                      wlds, y + (size_t)(S1_PHU1 + off) * NPOS, p,
                      sumA, sumqA, S1_PHU1 + off, red);
    } else {                 // phl1: xp[5:7] (20) -> 10+10
        int off = (yb - 14) * MT;
        stage_w<20, 20>(w_phl1 + off * 20, wlds);
        const float* xb = xp + ((size_t)b * 70 + 50) * HW + s;
        conv4<20, 20>([&](int c) { return ld4(xb + c * HW); },
                      wlds, y + (size_t)(S1_PHL1 + off) * NPOS, p,
                      sumA, sumqA, S1_PHL1 + off, red);
    }
}

// ---------------------------------------------------------------------------
// scale/shift from accumulated stats
// ---------------------------------------------------------------------------
__global__ void scale_kernel(int stage,
    const float* __restrict__ bn_hf1, const float* __restrict__ bn_hf2,
    const float* __restrict__ bn_phu1, const float* __restrict__ bn_phu2,
    const float* __restrict__ bn_phl1, const float* __restrict__ bn_phl2,
    const float* __restrict__ bn_fd1, const float* __restrict__ bn_fd2,
    const float* __restrict__ bn_hd1, const float* __restrict__ bn_hd2,
    const float* __restrict__ bn_fu, const float* __restrict__ bn_hu,
    const float* __restrict__ bn_pu, float* __restrict__ ws)
{
    int t = threadIdx.x;
    float* sumA   = ws + (size_t)NSLOT * NPOS;
    float* sumqA  = sumA + NSTAT;
    float* scaleA = sumqA + NSTAT;
    float* shiftA = scaleA + NSTAT;
    int stat, local, co;
    const float* bn;
    if (stage == 1) {
        if (t >= 160) return;
        stat = t;
        if      (t < 20) { bn = bn_hf1;  local = t;      co = 20; }
        else if (t < 50) { bn = bn_fd1;  local = t - 20; co = 30; }
        else if (t < 70) { bn = bn_phu1; local = t - 50; co = 20; }
        else if (t < 90) { bn = bn_phl1; local = t - 70; co = 20; }
        else             { bn = bn_hd1;  local = t - 90; co = 70; }
    } else if (stage == 2) {
        if (t >= 130) return;
        stat = 160 + t;
        if      (t < 10) { bn = bn_hf2;  local = t;      co = 10; }
        else if (t < 40) { bn = bn_fd2;  local = t - 10; co = 30; }
        else if (t < 50) { bn = bn_phu2; local = t - 40; co = 10; }
        else if (t < 60) { bn = bn_phl2; local = t - 50; co = 10; }
        else             { bn = bn_hd2;  local = t - 60; co = 70; }
    } else {
        if (t >= 120) return;
        stat = 290 + t;
        if      (t < 20) { bn = bn_fu; local = t;      co = 20; }
        else if (t < 50) { bn = bn_hu; local = t - 20; co = 30; }
        else             { bn = bn_pu; local = t - 50; co = 70; }
    }
    float n  = (float)NPOS;
    float m  = sumA[stat] / n;
    float v  = sumqA[stat] / n - m * m;
    float g  = bn[local];
    float bt = bn[co + local];
    float sc = g * rsqrtf(v + EPSV);
    scaleA[stat] = sc;
    shiftA[stat] = bt - m * sc;
}

// ---------------------------------------------------------------------------
// Stage 2 (heavy-first): hd2(0..6), fd2(7..9), hf2(10), phu2(11), phl2(12)
// ---------------------------------------------------------------------------
__global__ void __launch_bounds__(256, 3) stage2_kernel(
    const float* __restrict__ w_hf2, const float* __restrict__ w_fd2,
    const float* __restrict__ w_phu2, const float* __restrict__ w_phl2,
    const float* __restrict__ w_hd2, float* __restrict__ ws)
{
    __shared__ __align__(16) float wlds[MT * 72];
    __shared__ float red[4 * MT * 2];
    __shared__ float ssc[160], ssh[160];
    int g = blockIdx.x * 256 + threadIdx.x;
    int p = g * 4;
    float* y     = ws;
    float* sumA  = ws + (size_t)NSLOT * NPOS;
    float* sumqA = sumA + NSTAT;
    const float* scaleA = sumqA + NSTAT;
    const float* shiftA = scaleA + NSTAT;

    for (int i = threadIdx.x; i < 160; i += 256) { ssc[i] = scaleA[i]; ssh[i] = shiftA[i]; }
    int yb = blockIdx.y;

    if (yb < 7) {            // hd2: hd1(70) -> 7 x 10
        int off = yb * MT;
        stage_w<70, 72>(w_hd2 + off * 70, wlds);
        const float* src = y + (size_t)S1_HD1 * NPOS + p;
        conv4<70, 72>([&](int c) {
            return bnrelu4(ld4(src + (size_t)c * NPOS), ssc[S1_HD1 + c], ssh[S1_HD1 + c]); },
            wlds, y + (size_t)(S2_HD2 + off) * NPOS, p, sumA, sumqA, S2_HD2 + off, red);
    } else if (yb < 10) {    // fd2: fd1(30) -> 3 x 10
        int off = (yb - 7) * MT;
        stage_w<30, 32>(w_fd2 + off * 30, wlds);
        const float* src = y + (size_t)S1_FD1 * NPOS + p;
        conv4<30, 32>([&](int c) {
            return bnrelu4(ld4(src + (size_t)c * NPOS), ssc[S1_FD1 + c], ssh[S1_FD1 + c]); },
            wlds, y + (size_t)(S2_FD2 + off) * NPOS, p, sumA, sumqA, S2_FD2 + off, red);
    } else if (yb == 10) {   // hf2: hf1(20) -> 10
        stage_w<20, 20>(w_hf2, wlds);
        const float* src = y + (size_t)S1_HF1 * NPOS + p;
        conv4<20, 20>([&](int c) {
            return bnrelu4(ld4(src + (size_t)c * NPOS), ssc[S1_HF1 + c], ssh[S1_HF1 + c]); },
            wlds, y + (size_t)S2_HF2 * NPOS, p, sumA, sumqA, S2_HF2, red);
    } else if (yb == 11) {   // phu2: phu1(20) -> 10
        stage_w<20, 20>(w_phu2, wlds);
        const float* src = y + (size_t)S1_PHU1 * NPOS + p;
        conv4<20, 20>([&](int c) {
            return bnrelu4(ld4(src + (size_t)c * NPOS), ssc[S1_PHU1 + c], ssh[S1_PHU1 + c]); },
            wlds, y + (size_t)S2_PHU2 * NPOS, p, sumA, sumqA, S2_PHU2, red);
    } else {                 // phl2: phl1(20) -> 10
        stage_w<20, 20>(w_phl2, wlds);
        const float* src = y + (size_t)S1_PHL1 * NPOS + p;
        conv4<20, 20>([&](int c) {
            return bnrelu4(ld4(src + (size_t)c * NPOS), ssc[S1_PHL1 + c], ssh[S1_PHL1 + c]); },
            wlds, y + (size_t)S2_PHL2 * NPOS, p, sumA, sumqA, S2_PHL2, red);
    }
}

// ---------------------------------------------------------------------------
// Stage 3 (heavy-first): pu(0..6), hu(7..9), fu(10,11)
// ---------------------------------------------------------------------------
__global__ void __launch_bounds__(256, 3) stage3_kernel(
    const float* __restrict__ xp, const float* __restrict__ xh,
    const float* __restrict__ xf, const float* __restrict__ p_fea,
    const float* __restrict__ h_fea, const float* __restrict__ f_fea,
    const float* __restrict__ w_fu, const float* __restrict__ w_hu,
    const float* __restrict__ w_pu, float* __restrict__ ws)
{
    __shared__ __align__(16) float wlds[MT * 316];
    __shared__ float red[4 * MT * 2];
    __shared__ float ssc[130], ssh[130];             // stage-2 stat range
    int g = blockIdx.x * 256 + threadIdx.x;
    int p = g * 4;
    int b = (p >= HW) ? 1 : 0;
    int s = p - b * HW;
    float* y     = ws;
    float* sumA  = ws + (size_t)NSLOT * NPOS;
    float* sumqA = sumA + NSTAT;
    const float* scaleA = sumqA + NSTAT;
    const float* shiftA = scaleA + NSTAT;

    for (int i = threadIdx.x; i < 130; i += 256) {
        ssc[i] = scaleA[L2OFF + i]; ssh[i] = shiftA[L2OFF + i];
    }
    int yb = blockIdx.y;

    if (yb < 7) {            // pu: [p_fea; xp_new(60)] (316) -> 7 x 10
        int off = yb * MT;
        stage_w<316, 316>(w_pu + off * 316, wlds);
        const float* pb   = p_fea + (size_t)b * 256 * HW + s;
        const float* yhd2 = y + (size_t)S2_HD2 * NPOS + p;
        const float* xpb  = xp + ((size_t)b * 70 + 10) * HW + s;
        conv4<316, 316>([&](int c) {
            if (c < 256) return ld4(pb + c * HW);
            int cc = c - 256;
            float4 v = bnrelu4(ld4(yhd2 + (size_t)(10 + cc) * NPOS),
                               ssc[S2_HD2 - L2OFF + 10 + cc], ssh[S2_HD2 - L2OFF + 10 + cc]);
            float4 r0 = ld4(xpb + cc * HW);
            return make_float4(v.x + r0.x, v.y + r0.y, v.z + r0.z, v.w + r0.w); },
            wlds, y + (size_t)(S3_PU + off) * NPOS, p, sumA, sumqA, ST3_PU + off, red);
    } else if (yb < 10) {    // hu: [h_fea; xhu; xhl] (276) -> 3 x 10
        int off = (yb - 7) * MT;
        stage_w<276, 276>(w_hu + off * 276, wlds);
        const float* hb    = h_fea + (size_t)b * 256 * HW + s;
        const float* yphu2 = y + (size_t)S2_PHU2 * NPOS + p;
        const float* yphl2 = y + (size_t)S2_PHL2 * NPOS + p;
        const float* yfd2  = y + (size_t)S2_FD2 * NPOS + p;
        const float* xh1b  = xh + ((size_t)b * 30 + 10) * HW + s;
        conv4<276, 276>([&](int c) {
            if (c < 256) return ld4(hb + c * HW);
            if (c < 266) {
                int cc = c - 256;
                float4 a = bnrelu4(ld4(yphu2 + (size_t)cc * NPOS),
                                   ssc[S2_PHU2 - L2OFF + cc], ssh[S2_PHU2 - L2OFF + cc]);
                float4 f = bnrelu4(ld4(yfd2 + (size_t)(10 + cc) * NPOS),
                                   ssc[S2_FD2 - L2OFF + 10 + cc], ssh[S2_FD2 - L2OFF + 10 + cc]);
                float4 r0 = ld4(xh1b + cc * HW);
                return make_float4(r0.x + a.x + f.x, r0.y + a.y + f.y,
                                   r0.z + a.z + f.z, r0.w + a.w + f.w);
            }
            int cc = c - 266;
            float4 a = bnrelu4(ld4(yphl2 + (size_t)cc * NPOS),
                               ssc[S2_PHL2 - L2OFF + cc], ssh[S2_PHL2 - L2OFF + cc]);
            float4 f = bnrelu4(ld4(yfd2 + (size_t)(20 + cc) * NPOS),
                               ssc[S2_FD2 - L2OFF + 20 + cc], ssh[S2_FD2 - L2OFF + 20 + cc]);
            float4 r0 = ld4(xh1b + (10 + cc) * HW);
            return make_float4(r0.x + a.x + f.x, r0.y + a.y + f.y,
                               r0.z + a.z + f.z, r0.w + a.w + f.w); },
            wlds, y + (size_t)(S3_HU + off) * NPOS, p, sumA, sumqA, ST3_HU + off, red);
    } else {                 // fu: [f_fea; xf_new] (266) -> 10+10
        int off = (yb - 10) * MT;
        stage_w<266, 268>(w_fu + off * 266, wlds);
        const float* fb   = f_fea + (size_t)b * 256 * HW + s;
        const float* yhf2 = y + (size_t)S2_HF2 * NPOS + p;
        const float* xf1  = xf + ((size_t)b * 20 + 10) * HW + s;
        conv4<266, 268>([&](int c) {
            if (c < 256) return ld4(fb + c * HW);
            int cc = c - 256;
            float4 v = bnrelu4(ld4(yhf2 + (size_t)cc * NPOS),
                               ssc[S2_HF2 - L2OFF + cc], ssh[S2_HF2 - L2OFF + cc]);
            float4 r0 = ld4(xf1 + cc * HW);
            return make_float4(v.x + r0.x, v.y + r0.y, v.z + r0.z, v.w + r0.w); },
            wlds, y + (size_t)(S3_FU + off) * NPOS, p, sumA, sumqA, ST3_FU + off, red);
    }
}

// ---------------------------------------------------------------------------
// Final: bn+relu all 220 output channels, float4
// out = concat([xp_upd(70), xh_upd(30), xf_upd(20), xfh(30), xhp(70)])
// ---------------------------------------------------------------------------
__global__ void __launch_bounds__(256) final_kernel(const float* __restrict__ ws,
                                                    float* __restrict__ out)
{
    int g = blockIdx.x * 256 + threadIdx.x;
    int p = g * 4;
    int c = blockIdx.y;
    const float* sumA   = ws + (size_t)NSLOT * NPOS;
    const float* scaleA = sumA + 2 * NSTAT;
    const float* shiftA = scaleA + NSTAT;
    int slot, stat;
    if      (c < 70)  { slot = S3_PU  + c;         stat = ST3_PU  + c;         }
    else if (c < 100) { slot = S3_HU  + (c - 70);  stat = ST3_HU  + (c - 70);  }
    else if (c < 120) { slot = S3_FU  + (c - 100); stat = ST3_FU  + (c - 100); }
    else if (c < 150) { slot = S2_FD2 + (c - 120); stat = S2_FD2 + (c - 120);  }
    else              { slot = S2_HD2 + (c - 150); stat = S2_HD2 + (c - 150);  }
    float4 v = *(const float4*)(ws + (size_t)slot * NPOS + p);
    float sc = scaleA[stat], sh = shiftA[stat];
    v.x = fmaf(v.x, sc, sh); v.x = v.x > 0.f ? v.x : 0.f;
    v.y = fmaf(v.y, sc, sh); v.y = v.y > 0.f ? v.y : 0.f;
    v.z = fmaf(v.z, sc, sh); v.z = v.z > 0.f ? v.z : 0.f;
    v.w = fmaf(v.w, sc, sh); v.w = v.w > 0.f ? v.w : 0.f;
    int b = (p >= HW) ? 1 : 0;
    int s = p - b * HW;
    *(float4*)(out + ((size_t)b * 220 + c) * HW + s) = v;
}

// ---------------------------------------------------------------------------
extern "C" void kernel_launch(void* const* d_in, const int* in_sizes, int n_in,
                              void* d_out, int out_size, void* d_ws, size_t ws_size,
                              hipStream_t stream)
{
    const float* xp     = (const float*)d_in[0];
    const float* xh     = (const float*)d_in[1];
    const float* xf     = (const float*)d_in[2];
    const float* p_fea  = (const float*)d_in[3];
    const float* h_fea  = (const float*)d_in[4];
    const float* f_fea  = (const float*)d_in[5];
    const float* w_hf1  = (const float*)d_in[6];  const float* bn_hf1  = (const float*)d_in[7];
    const float* w_hf2  = (const float*)d_in[8];  const float* bn_hf2  = (const float*)d_in[9];
    const float* w_phu1 = (const float*)d_in[10]; const float* bn_phu1 = (const float*)d_in[11];
    const float* w_phu2 = (const float*)d_in[12]; const float* bn_phu2 = (const float*)d_in[13];
    const float* w_phl1 = (const float*)d_in[14]; const float* bn_phl1 = (const float*)d_in[15];
    const float* w_phl2 = (const float*)d_in[16]; const float* bn_phl2 = (const float*)d_in[17];
    const float* w_fd1  = (const float*)d_in[18]; const float* bn_fd1  = (const float*)d_in[19];
    const float* w_fd2  = (const float*)d_in[20]; const float* bn_fd2  = (const float*)d_in[21];
    const float* w_hd1  = (const float*)d_in[22]; const float* bn_hd1  = (const float*)d_in[23];
    const float* w_hd2  = (const float*)d_in[24]; const float* bn_hd2  = (const float*)d_in[25];
    const float* w_fu   = (const float*)d_in[26]; const float* bn_fu   = (const float*)d_in[27];
    const float* w_hu   = (const float*)d_in[28]; const float* bn_hu   = (const float*)d_in[29];
    const float* w_pu   = (const float*)d_in[30]; const float* bn_pu   = (const float*)d_in[31];

    float* ws  = (float*)d_ws;
    float* out = (float*)d_out;

    size_t need_bytes = ((size_t)NSLOT * NPOS + 4 * NSTAT) * sizeof(float);
    if (ws_size < need_bytes) return;

    hipMemsetAsync(ws + (size_t)NSLOT * NPOS, 0, 2 * NSTAT * sizeof(float), stream);

    dim3 blk(256);
    const int GX = NPOS / 1024;   // 72 x-blocks, 4 positions/thread
    stage1_kernel<<<dim3(GX, 16), blk, 0, stream>>>(xp, xh, xf, p_fea, h_fea,
                                                    w_hf1, w_fd1, w_phu1, w_phl1, w_hd1, ws);
    scale_kernel<<<1, 256, 0, stream>>>(1, bn_hf1, bn_hf2, bn_phu1, bn_phu2, bn_phl1, bn_phl2,
                                        bn_fd1, bn_fd2, bn_hd1, bn_hd2, bn_fu, bn_hu, bn_pu, ws);
    stage2_kernel<<<dim3(GX, 13), blk, 0, stream>>>(w_hf2, w_fd2, w_phu2, w_phl2, w_hd2, ws);
    scale_kernel<<<1, 256, 0, stream>>>(2, bn_hf1, bn_hf2, bn_phu1, bn_phu2, bn_phl1, bn_phl2,
                                        bn_fd1, bn_fd2, bn_hd1, bn_hd2, bn_fu, bn_hu, bn_pu, ws);
    stage3_kernel<<<dim3(GX, 12), blk, 0, stream>>>(xp, xh, xf, p_fea, h_fea, f_fea,
                                                    w_fu, w_hu, w_pu, ws);
    scale_kernel<<<1, 256, 0, stream>>>(3, bn_hf1, bn_hf2, bn_phu1, bn_phu2, bn_phl1, bn_phl2,
                                        bn_fd1, bn_fd2, bn_hd1, bn_hd2, bn_fu, bn_hu, bn_pu, ws);
    final_kernel<<<dim3(NPOS / 1024, 220), blk, 0, stream>>>(ws, out);
}

// Round 5
// 635.111 us; speedup vs baseline: 2.5486x; 2.5486x over previous
//
#include <hip/hip_runtime.h>
#include <stdint.h>

#define HW   36864      // 192*192
#define NPOS 73728      // B*HW, B=2
#define EPSV 1e-5f

// channel-slot layout in workspace (each slot = NPOS floats)
#define S1_HF1  0
#define S1_FD1  20
#define S1_PHU1 50
#define S1_PHL1 70
#define S1_HD1  90
#define S2_HF2  160
#define S2_FD2  170
#define S2_PHU2 200
#define S2_PHL2 210
#define S2_HD2  220
#define S3_FU   0       // reuse stage-1 slots (dead by stage 3)
#define S3_HU   20
#define S3_PU   50
#define ST3_FU  290
#define ST3_HU  310
#define ST3_PU  340
#define NSLOT 290
#define NSTAT 410
#define L2OFF 160

#define MT 10           // output channels per block

__device__ __forceinline__ float4 ld4(const float* p) { return *(const float4*)p; }

__device__ __forceinline__ float4 bnrelu4(float4 v, float sc, float sh) {
    float4 r;
    r.x = fmaf(v.x, sc, sh); r.y = fmaf(v.y, sc, sh);
    r.z = fmaf(v.z, sc, sh); r.w = fmaf(v.w, sc, sh);
    r.x = r.x > 0.f ? r.x : 0.f;
    r.y = r.y > 0.f ? r.y : 0.f;
    r.z = r.z > 0.f ? r.z : 0.f;
    r.w = r.w > 0.f ? r.w : 0.f;
    return r;
}

__device__ __forceinline__ float4 add4(float4 a, float4 b) {
    return make_float4(a.x + b.x, a.y + b.y, a.z + b.z, a.w + b.w);
}

// async 16B/lane global->LDS; lane i's data lands at lds_base + i*16.
// In-flight data costs ZERO VGPRs -> the register allocator cannot
// serialize the pipeline (r3/r4 failure mode).
__device__ __forceinline__ void gld_lds16(const float* g, float* l)
{
    __builtin_amdgcn_global_load_lds(
        (const __attribute__((address_space(1))) uint32_t*)g,
        (__attribute__((address_space(3))) uint32_t*)l,
        16, 0, 0);
}

template<int CIN, int CINP>
__device__ __forceinline__ void stage_w(const float* __restrict__ w, float* wl)
{
    if (CIN == CINP) {
        for (int idx = threadIdx.x; idx < MT * CIN; idx += 256)
            wl[idx] = w[idx];
    } else {
        for (int idx = threadIdx.x; idx < MT * CIN; idx += 256) {
            int o = idx / CIN;
            int c = idx - o * CIN;
            wl[o * CINP + c] = w[idx];
        }
    }
    __syncthreads();
}

// 4 channels x 4 positions for one output channel, channel-ascending
__device__ __forceinline__ void fma4x4(float4& a, float4 w, const float4* buf)
{
    a.x = fmaf(w.x, buf[0].x, a.x); a.y = fmaf(w.x, buf[0].y, a.y);
    a.z = fmaf(w.x, buf[0].z, a.z); a.w = fmaf(w.x, buf[0].w, a.w);
    a.x = fmaf(w.y, buf[1].x, a.x); a.y = fmaf(w.y, buf[1].y, a.y);
    a.z = fmaf(w.y, buf[1].z, a.z); a.w = fmaf(w.y, buf[1].w, a.w);
    a.x = fmaf(w.z, buf[2].x, a.x); a.y = fmaf(w.z, buf[2].y, a.y);
    a.z = fmaf(w.z, buf[2].z, a.z); a.w = fmaf(w.z, buf[2].w, a.w);
    a.x = fmaf(w.w, buf[3].x, a.x); a.y = fmaf(w.w, buf[3].y, a.y);
    a.z = fmaf(w.w, buf[3].z, a.z); a.w = fmaf(w.w, buf[3].w, a.w);
}

__device__ __forceinline__ void fma1(float4& a, float w, float4 x)
{
    a.x = fmaf(w, x.x, a.x); a.y = fmaf(w, x.y, a.y);
    a.z = fmaf(w, x.z, a.z); a.w = fmaf(w, x.w, a.w);
}

// shared epilogue: y store + per-channel sum/sumsq reduction
__device__ __forceinline__ void finish(float4* acc, float* yo, int p,
                                       float* sumA, float* sumqA, int stat0,
                                       float* red)
{
#pragma unroll
    for (int o = 0; o < MT; ++o)
        *(float4*)(yo + (size_t)o * NPOS + p) = acc[o];
    int lane = threadIdx.x & 63;
    int wv_  = threadIdx.x >> 6;
#pragma unroll
    for (int o = 0; o < MT; ++o) {
        float s_ = (acc[o].x + acc[o].y) + (acc[o].z + acc[o].w);
        float q  = (acc[o].x * acc[o].x + acc[o].y * acc[o].y)
                 + (acc[o].z * acc[o].z + acc[o].w * acc[o].w);
#pragma unroll
        for (int i = 1; i < 64; i <<= 1) {
            s_ += __shfl_xor(s_, i, 64);
            q  += __shfl_xor(q, i, 64);
        }
        if (lane == 0) {
            red[(wv_ * MT + o) * 2]     = s_;
            red[(wv_ * MT + o) * 2 + 1] = q;
        }
    }
    __syncthreads();
    if (threadIdx.x < MT) {
        int o = threadIdx.x;
        float s_ = 0.f, q = 0.f;
#pragma unroll
        for (int k = 0; k < 4; ++k) {
            s_ += red[(k * MT + o) * 2];
            q  += red[(k * MT + o) * 2 + 1];
        }
        atomicAdd(&sumA[stat0 + o], s_);
        atomicAdd(&sumqA[stat0 + o], q);
    }
}

// ---------------------------------------------------------------------------
// Per-wave async staging pipeline. Wave-private LDS region: 3 buffers x
// 4 slots x 1KB. Issue 2 chunks ahead; counted vmcnt(4)/vmcnt(0) (immediates,
// per-wave, no barriers). gp(j) -> per-lane global address of staged slot j;
// cons(k, buf) consumes chunk k (slots 4k..4k+3) from LDS.
// ---------------------------------------------------------------------------
template<int NCHUNK, class GP, class CONS>
__device__ __forceinline__ void pipe_loop(float* wstage, GP gp, CONS cons)
{
    static_assert(NCHUNK >= 2, "pipe_loop needs >=2 chunks");
#pragma unroll
    for (int i = 0; i < 4; ++i) gld_lds16(gp(i), wstage + i * 256);
#pragma unroll
    for (int i = 0; i < 4; ++i) gld_lds16(gp(4 + i), wstage + 1024 + i * 256);
    int obuf = 2, cbuf = 0;
#pragma unroll 1
    for (int k = 0; k <= NCHUNK - 3; ++k) {
        asm volatile("s_waitcnt vmcnt(4)" ::: "memory");   // chunk k landed
        float* dst = wstage + obuf * 1024;
        int j0 = (k + 2) * 4;
#pragma unroll
        for (int i = 0; i < 4; ++i) gld_lds16(gp(j0 + i), dst + i * 256);
        cons(k, wstage + cbuf * 1024);
        obuf = (obuf == 2) ? 0 : obuf + 1;
        cbuf = (cbuf == 2) ? 0 : cbuf + 1;
    }
    asm volatile("s_waitcnt vmcnt(4)" ::: "memory");
    cons(NCHUNK - 2, wstage + cbuf * 1024);
    cbuf = (cbuf == 2) ? 0 : cbuf + 1;
    asm volatile("s_waitcnt vmcnt(0)" ::: "memory");
    cons(NCHUNK - 1, wstage + cbuf * 1024);
}

// ---------------------------------------------------------------------------
// Register-path conv for small CIN (r3-proven). Single 8-chunk prefetch.
// ---------------------------------------------------------------------------
template<int CIN, int CINP, class F>
__device__ __forceinline__ void conv4s(F fetch, const float* wl,
                                       float* __restrict__ y, int p,
                                       float* __restrict__ sumA,
                                       float* __restrict__ sumqA,
                                       int stat0, float* red)
{
    float4 acc[MT];
#pragma unroll
    for (int o = 0; o < MT; ++o) acc[o] = make_float4(0.f, 0.f, 0.f, 0.f);

    constexpr int CHUNK = 8;
    constexpr int MAIN = (CIN / CHUNK) * CHUNK;
    if (MAIN > 0) {
        float4 buf[CHUNK];
#pragma unroll
        for (int i = 0; i < CHUNK; ++i) buf[i] = fetch(i);
#pragma unroll 1
        for (int c0 = CHUNK; c0 < MAIN; c0 += CHUNK) {
            float4 nxt[CHUNK];
#pragma unroll
            for (int i = 0; i < CHUNK; ++i) nxt[i] = fetch(c0 + i);
            const float* wb = wl + (c0 - CHUNK);
#pragma unroll
            for (int o = 0; o < MT; ++o) {
                fma4x4(acc[o], ld4(wb + o * CINP), buf);
                fma4x4(acc[o], ld4(wb + o * CINP + 4), buf + 4);
            }
#pragma unroll
            for (int i = 0; i < CHUNK; ++i) buf[i] = nxt[i];
        }
        const float* wb = wl + (MAIN - CHUNK);
#pragma unroll
        for (int o = 0; o < MT; ++o) {
            fma4x4(acc[o], ld4(wb + o * CINP), buf);
            fma4x4(acc[o], ld4(wb + o * CINP + 4), buf + 4);
        }
    }
    constexpr int REM = CIN - MAIN;
    int ct = MAIN;
    if (REM >= 4) {
        float4 buf4[4];
#pragma unroll
        for (int i = 0; i < 4; ++i) buf4[i] = fetch(ct + i);
#pragma unroll
        for (int o = 0; o < MT; ++o)
            fma4x4(acc[o], ld4(wl + ct + o * CINP), buf4);
        ct += 4;
    }
#pragma unroll
    for (int c = ct; c < CIN; ++c) {
        float4 x = fetch(c);
#pragma unroll
        for (int o = 0; o < MT; ++o)
            fma1(acc[o], wl[o * CINP + c], x);
    }
    finish(acc, y, p, sumA, sumqA, stat0, red);
}

// ---------------------------------------------------------------------------
// Stage 1 (heavy-first): hd1(0..6) staged, fd1(7..9) staged, hf1/phu1/phl1 reg
// ---------------------------------------------------------------------------
__global__ void __launch_bounds__(256, 2) stage1_kernel(
    const float* __restrict__ xp, const float* __restrict__ xh,
    const float* __restrict__ xf, const float* __restrict__ p_fea,
    const float* __restrict__ h_fea,
    const float* __restrict__ w_hf1, const float* __restrict__ w_fd1,
    const float* __restrict__ w_phu1, const float* __restrict__ w_phl1,
    const float* __restrict__ w_hd1, float* __restrict__ ws)
{
    __shared__ __align__(16) float stagebuf[4 * 3072];   // 48KB: 4 waves x 3 bufs x 4KB
    __shared__ __align__(16) float wlds[MT * 276];
    __shared__ float red[4 * MT * 2];
    int g = blockIdx.x * 256 + threadIdx.x;
    int p = g * 4;
    int b = (p >= HW) ? 1 : 0;
    int s = p - b * HW;
    float* y     = ws;
    float* sumA  = ws + (size_t)NSLOT * NPOS;
    float* sumqA = sumA + NSTAT;
    float* wstage = stagebuf + (threadIdx.x >> 6) * 3072;
    int lane4 = (threadIdx.x & 63) * 4;
    int yb = blockIdx.y;

    if (yb < 7) {            // hd1: [p_fea; xh1; xh2] (276) staged, 69 chunks
        int off = yb * MT;
        stage_w<276, 276>(w_hd1 + off * 276, wlds);
        const float* pb = p_fea + (size_t)b * 256 * HW + s;
        const float* xb = xh + ((size_t)b * 30 + 10) * HW + s;
        float4 acc[MT];
#pragma unroll
        for (int o = 0; o < MT; ++o) acc[o] = make_float4(0.f, 0.f, 0.f, 0.f);
        auto gp = [&](int j) -> const float* {
            return (j < 256) ? pb + (size_t)j * HW : xb + (size_t)(j - 256) * HW; };
        pipe_loop<69>(wstage, gp, [&](int k, float* bb) {
            float4 xs[4];
#pragma unroll
            for (int i = 0; i < 4; ++i) xs[i] = *(float4*)(bb + i * 256 + lane4);
#pragma unroll
            for (int o = 0; o < MT; ++o)
                fma4x4(acc[o], ld4(wlds + o * 276 + k * 4), xs);
        });
        finish(acc, y + (size_t)(S1_HD1 + off) * NPOS, p, sumA, sumqA, S1_HD1 + off, red);
    } else if (yb < 10) {    // fd1: [h_fea; xf1] (266): 264 staged + 2 reg tail
        int off = (yb - 7) * MT;
        stage_w<266, 268>(w_fd1 + off * 266, wlds);
        const float* hb  = h_fea + (size_t)b * 256 * HW + s;
        const float* xf1 = xf + ((size_t)b * 20 + 10) * HW + s;
        float4 acc[MT];
#pragma unroll
        for (int o = 0; o < MT; ++o) acc[o] = make_float4(0.f, 0.f, 0.f, 0.f);
        auto gp = [&](int j) -> const float* {
            return (j < 256) ? hb + (size_t)j * HW : xf1 + (size_t)(j - 256) * HW; };
        pipe_loop<66>(wstage, gp, [&](int k, float* bb) {
            float4 xs[4];
#pragma unroll
            for (int i = 0; i < 4; ++i) xs[i] = *(float4*)(bb + i * 256 + lane4);
#pragma unroll
            for (int o = 0; o < MT; ++o)
                fma4x4(acc[o], ld4(wlds + o * 268 + k * 4), xs);
        });
        float4 t0 = ld4(xf1 + (size_t)8 * HW);
        float4 t1 = ld4(xf1 + (size_t)9 * HW);
#pragma unroll
        for (int o = 0; o < MT; ++o) {
            fma1(acc[o], wlds[o * 268 + 264], t0);
            fma1(acc[o], wlds[o * 268 + 265], t1);
        }
        finish(acc, y + (size_t)(S1_FD1 + off) * NPOS, p, sumA, sumqA, S1_FD1 + off, red);
    } else if (yb < 12) {    // hf1 (20) register path
        int off = (yb - 10) * MT;
        stage_w<20, 20>(w_hf1 + off * 20, wlds);
        const float* xb = xh + ((size_t)b * 30 + 10) * HW + s;
        conv4s<20, 20>([&](int c) { return ld4(xb + c * HW); },
                       wlds, y + (size_t)(S1_HF1 + off) * NPOS, p,
                       sumA, sumqA, S1_HF1 + off, red);
    } else if (yb < 14) {    // phu1 (40) register path
        int off = (yb - 12) * MT;
        stage_w<40, 40>(w_phu1 + off * 40, wlds);
        const float* xb = xp + ((size_t)b * 70 + 10) * HW + s;
        conv4s<40, 40>([&](int c) { return ld4(xb + c * HW); },
                       wlds, y + (size_t)(S1_PHU1 + off) * NPOS, p,
                       sumA, sumqA, S1_PHU1 + off, red);
    } else {                 // phl1 (20) register path
        int off = (yb - 14) * MT;
        stage_w<20, 20>(w_phl1 + off * 20, wlds);
        const float* xb = xp + ((size_t)b * 70 + 50) * HW + s;
        conv4s<20, 20>([&](int c) { return ld4(xb + c * HW); },
                       wlds, y + (size_t)(S1_PHL1 + off) * NPOS, p,
                       sumA, sumqA, S1_PHL1 + off, red);
    }
}

// ---------------------------------------------------------------------------
__global__ void scale_kernel(int stage,
    const float* __restrict__ bn_hf1, const float* __restrict__ bn_hf2,
    const float* __restrict__ bn_phu1, const float* __restrict__ bn_phu2,
    const float* __restrict__ bn_phl1, const float* __restrict__ bn_phl2,
    const float* __restrict__ bn_fd1, const float* __restrict__ bn_fd2,
    const float* __restrict__ bn_hd1, const float* __restrict__ bn_hd2,
    const float* __restrict__ bn_fu, const float* __restrict__ bn_hu,
    const float* __restrict__ bn_pu, float* __restrict__ ws)
{
    int t = threadIdx.x;
    float* sumA   = ws + (size_t)NSLOT * NPOS;
    float* sumqA  = sumA + NSTAT;
    float* scaleA = sumqA + NSTAT;
    float* shiftA = scaleA + NSTAT;
    int stat, local, co;
    const float* bn;
    if (stage == 1) {
        if (t >= 160) return;
        stat = t;
        if      (t < 20) { bn = bn_hf1;  local = t;      co = 20; }
        else if (t < 50) { bn = bn_fd1;  local = t - 20; co = 30; }
        else if (t < 70) { bn = bn_phu1; local = t - 50; co = 20; }
        else if (t < 90) { bn = bn_phl1; local = t - 70; co = 20; }
        else             { bn = bn_hd1;  local = t - 90; co = 70; }
    } else if (stage == 2) {
        if (t >= 130) return;
        stat = 160 + t;
        if      (t < 10) { bn = bn_hf2;  local = t;      co = 10; }
        else if (t < 40) { bn = bn_fd2;  local = t - 10; co = 30; }
        else if (t < 50) { bn = bn_phu2; local = t - 40; co = 10; }
        else if (t < 60) { bn = bn_phl2; local = t - 50; co = 10; }
        else             { bn = bn_hd2;  local = t - 60; co = 70; }
    } else {
        if (t >= 120) return;
        stat = 290 + t;
        if      (t < 20) { bn = bn_fu; local = t;      co = 20; }
        else if (t < 50) { bn = bn_hu; local = t - 20; co = 30; }
        else             { bn = bn_pu; local = t - 50; co = 70; }
    }
    float n  = (float)NPOS;
    float m  = sumA[stat] / n;
    float v  = sumqA[stat] / n - m * m;
    float g  = bn[local];
    float bt = bn[co + local];
    float sc = g * rsqrtf(v + EPSV);
    scaleA[stat] = sc;
    shiftA[stat] = bt - m * sc;
}

// ---------------------------------------------------------------------------
// Stage 2 (heavy-first): hd2(0..6) staged, fd2(7..9)/hf2(10)/phu2(11)/phl2(12)
// ---------------------------------------------------------------------------
__global__ void __launch_bounds__(256, 2) stage2_kernel(
    const float* __restrict__ w_hf2, const float* __restrict__ w_fd2,
    const float* __restrict__ w_phu2, const float* __restrict__ w_phl2,
    const float* __restrict__ w_hd2, float* __restrict__ ws)
{
    __shared__ __align__(16) float stagebuf[4 * 3072];
    __shared__ __align__(16) float wlds[MT * 72];
    __shared__ float red[4 * MT * 2];
    __shared__ float ssc[160], ssh[160];
    int g = blockIdx.x * 256 + threadIdx.x;
    int p = g * 4;
    float* y     = ws;
    float* sumA  = ws + (size_t)NSLOT * NPOS;
    float* sumqA = sumA + NSTAT;
    const float* scaleA = sumqA + NSTAT;
    const float* shiftA = scaleA + NSTAT;
    float* wstage = stagebuf + (threadIdx.x >> 6) * 3072;
    int lane4 = (threadIdx.x & 63) * 4;

    for (int i = threadIdx.x; i < 160; i += 256) { ssc[i] = scaleA[i]; ssh[i] = shiftA[i]; }
    int yb = blockIdx.y;

    if (yb < 7) {            // hd2: hd1(70): 68 staged + 2 reg tail
        int off = yb * MT;
        stage_w<70, 72>(w_hd2 + off * 70, wlds);
        const float* src = y + (size_t)S1_HD1 * NPOS + p;
        float4 acc[MT];
#pragma unroll
        for (int o = 0; o < MT; ++o) acc[o] = make_float4(0.f, 0.f, 0.f, 0.f);
        auto gp = [&](int j) -> const float* { return src + (size_t)j * NPOS; };
        pipe_loop<17>(wstage, gp, [&](int k, float* bb) {
            float4 xs[4];
#pragma unroll
            for (int i = 0; i < 4; ++i) {
                int c = k * 4 + i;
                float4 v = *(float4*)(bb + i * 256 + lane4);
                xs[i] = bnrelu4(v, ssc[S1_HD1 + c], ssh[S1_HD1 + c]);
            }
#pragma unroll
            for (int o = 0; o < MT; ++o)
                fma4x4(acc[o], ld4(wlds + o * 72 + k * 4), xs);
        });
        float4 t0 = bnrelu4(ld4(src + (size_t)68 * NPOS), ssc[S1_HD1 + 68], ssh[S1_HD1 + 68]);
        float4 t1 = bnrelu4(ld4(src + (size_t)69 * NPOS), ssc[S1_HD1 + 69], ssh[S1_HD1 + 69]);
#pragma unroll
        for (int o = 0; o < MT; ++o) {
            fma1(acc[o], wlds[o * 72 + 68], t0);
            fma1(acc[o], wlds[o * 72 + 69], t1);
        }
        finish(acc, y + (size_t)(S2_HD2 + off) * NPOS, p, sumA, sumqA, S2_HD2 + off, red);
    } else if (yb < 10) {    // fd2: fd1(30) register path
        int off = (yb - 7) * MT;
        stage_w<30, 32>(w_fd2 + off * 30, wlds);
        const float* src = y + (size_t)S1_FD1 * NPOS + p;
        conv4s<30, 32>([&](int c) {
            return bnrelu4(ld4(src + (size_t)c * NPOS), ssc[S1_FD1 + c], ssh[S1_FD1 + c]); },
            wlds, y + (size_t)(S2_FD2 + off) * NPOS, p, sumA, sumqA, S2_FD2 + off, red);
    } else if (yb == 10) {   // hf2
        stage_w<20, 20>(w_hf2, wlds);
        const float* src = y + (size_t)S1_HF1 * NPOS + p;
        conv4s<20, 20>([&](int c) {
            return bnrelu4(ld4(src + (size_t)c * NPOS), ssc[S1_HF1 + c], ssh[S1_HF1 + c]); },
            wlds, y + (size_t)S2_HF2 * NPOS, p, sumA, sumqA, S2_HF2, red);
    } else if (yb == 11) {   // phu2
        stage_w<20, 20>(w_phu2, wlds);
        const float* src = y + (size_t)S1_PHU1 * NPOS + p;
        conv4s<20, 20>([&](int c) {
            return bnrelu4(ld4(src + (size_t)c * NPOS), ssc[S1_PHU1 + c], ssh[S1_PHU1 + c]); },
            wlds, y + (size_t)S2_PHU2 * NPOS, p, sumA, sumqA, S2_PHU2, red);
    } else {                 // phl2
        stage_w<20, 20>(w_phl2, wlds);
        const float* src = y + (size_t)S1_PHL1 * NPOS + p;
        conv4s<20, 20>([&](int c) {
            return bnrelu4(ld4(src + (size_t)c * NPOS), ssc[S1_PHL1 + c], ssh[S1_PHL1 + c]); },
            wlds, y + (size_t)S2_PHL2 * NPOS, p, sumA, sumqA, S2_PHL2, red);
    }
}

// ---------------------------------------------------------------------------
// Stage 3 (heavy-first): pu(0..6), hu(7..9), fu(10,11) — all staged.
// Composite channels staged as interleaved raw streams, combined post-LDS.
// ---------------------------------------------------------------------------
__global__ void __launch_bounds__(256, 2) stage3_kernel(
    const float* __restrict__ xp, const float* __restrict__ xh,
    const float* __restrict__ xf, const float* __restrict__ p_fea,
    const float* __restrict__ h_fea, const float* __restrict__ f_fea,
    const float* __restrict__ w_fu, const float* __restrict__ w_hu,
    const float* __restrict__ w_pu, float* __restrict__ ws)
{
    __shared__ __align__(16) float stagebuf[4 * 3072];
    __shared__ __align__(16) float wlds[MT * 316];
    __shared__ float red[4 * MT * 2];
    __shared__ float ssc[130], ssh[130];
    int g = blockIdx.x * 256 + threadIdx.x;
    int p = g * 4;
    int b = (p >= HW) ? 1 : 0;
    int s = p - b * HW;
    float* y     = ws;
    float* sumA  = ws + (size_t)NSLOT * NPOS;
    float* sumqA = sumA + NSTAT;
    const float* scaleA = sumqA + NSTAT;
    const float* shiftA = scaleA + NSTAT;
    float* wstage = stagebuf + (threadIdx.x >> 6) * 3072;
    int lane4 = (threadIdx.x & 63) * 4;

    for (int i = threadIdx.x; i < 130; i += 256) {
        ssc[i] = scaleA[L2OFF + i]; ssh[i] = shiftA[L2OFF + i];
    }
    int yb = blockIdx.y;

    if (yb < 7) {            // pu (316): 256 pure + 60 pairs (A=yhd2,B=xp), 94 chunks
        int off = yb * MT;
        stage_w<316, 316>(w_pu + off * 316, wlds);
        const float* pb   = p_fea + (size_t)b * 256 * HW + s;
        const float* yhd2 = y + (size_t)S2_HD2 * NPOS + p;
        const float* xpb  = xp + ((size_t)b * 70 + 10) * HW + s;
        float4 acc[MT];
#pragma unroll
        for (int o = 0; o < MT; ++o) acc[o] = make_float4(0.f, 0.f, 0.f, 0.f);
        auto gp = [&](int j) -> const float* {
            if (j < 256) return pb + (size_t)j * HW;
            int jj = j - 256, t = jj >> 1;
            return (jj & 1) ? xpb + (size_t)t * HW
                            : yhd2 + (size_t)(10 + t) * NPOS; };
        pipe_loop<94>(wstage, gp, [&](int k, float* bb) {
            if (k < 64) {
                float4 xs[4];
#pragma unroll
                for (int i = 0; i < 4; ++i) xs[i] = *(float4*)(bb + i * 256 + lane4);
#pragma unroll
                for (int o = 0; o < MT; ++o)
                    fma4x4(acc[o], ld4(wlds + o * 316 + k * 4), xs);
            } else {
                int t0 = (k - 64) * 2;
                float4 a0 = *(float4*)(bb + 0 * 256 + lane4);
                float4 b0 = *(float4*)(bb + 1 * 256 + lane4);
                float4 a1 = *(float4*)(bb + 2 * 256 + lane4);
                float4 b1 = *(float4*)(bb + 3 * 256 + lane4);
                int i0 = S2_HD2 - L2OFF + 10 + t0;
                float4 x0 = add4(bnrelu4(a0, ssc[i0], ssh[i0]), b0);
                float4 x1 = add4(bnrelu4(a1, ssc[i0 + 1], ssh[i0 + 1]), b1);
                int c0 = 256 + t0;
#pragma unroll
                for (int o = 0; o < MT; ++o) {
                    float2 w2 = *(const float2*)(wlds + o * 316 + c0);
                    fma1(acc[o], w2.x, x0);
                    fma1(acc[o], w2.y, x1);
                }
            }
        });
        finish(acc, y + (size_t)(S3_PU + off) * NPOS, p, sumA, sumqA, ST3_PU + off, red);
    } else if (yb < 10) {    // hu (276): 256 pure + 20 quads (A,F,R,pad), 84 chunks
        int off = (yb - 7) * MT;
        stage_w<276, 276>(w_hu + off * 276, wlds);
        const float* hb    = h_fea + (size_t)b * 256 * HW + s;
        const float* yphu2 = y + (size_t)S2_PHU2 * NPOS + p;
        const float* yphl2 = y + (size_t)S2_PHL2 * NPOS + p;
        const float* yfd2  = y + (size_t)S2_FD2 * NPOS + p;
        const float* xh1b  = xh + ((size_t)b * 30 + 10) * HW + s;
        float4 acc[MT];
#pragma unroll
        for (int o = 0; o < MT; ++o) acc[o] = make_float4(0.f, 0.f, 0.f, 0.f);
        auto gp = [&](int j) -> const float* {
            if (j < 256) return hb + (size_t)j * HW;
            int jj = j - 256, t = jj >> 2, r = jj & 3;
            if (r == 0) return (t < 10) ? yphu2 + (size_t)t * NPOS
                                        : yphl2 + (size_t)(t - 10) * NPOS;
            if (r == 1) return yfd2 + (size_t)(10 + t) * NPOS;
            return xh1b + (size_t)t * HW;      // r==2 real, r==3 pad
        };
        pipe_loop<84>(wstage, gp, [&](int k, float* bb) {
            if (k < 64) {
                float4 xs[4];
#pragma unroll
                for (int i = 0; i < 4; ++i) xs[i] = *(float4*)(bb + i * 256 + lane4);
#pragma unroll
                for (int o = 0; o < MT; ++o)
                    fma4x4(acc[o], ld4(wlds + o * 276 + k * 4), xs);
            } else {
                int t = k - 64, c = 256 + t;
                float4 A = *(float4*)(bb + 0 * 256 + lane4);
                float4 F = *(float4*)(bb + 1 * 256 + lane4);
                float4 R = *(float4*)(bb + 2 * 256 + lane4);
                int ia = (t < 10) ? (S2_PHU2 - L2OFF + t) : (S2_PHL2 - L2OFF + t - 10);
                int iff = S2_FD2 - L2OFF + 10 + t;
                float4 a = bnrelu4(A, ssc[ia], ssh[ia]);
                float4 f = bnrelu4(F, ssc[iff], ssh[iff]);
                float4 x = make_float4(R.x + a.x + f.x, R.y + a.y + f.y,
                                       R.z + a.z + f.z, R.w + a.w + f.w);
#pragma unroll
                for (int o = 0; o < MT; ++o)
                    fma1(acc[o], wlds[o * 276 + c], x);
            }
        });
        finish(acc, y + (size_t)(S3_HU + off) * NPOS, p, sumA, sumqA, ST3_HU + off, red);
    } else {                 // fu (266): 256 pure + 10 pairs (A=yhf2,B=xf1), 69 chunks
        int off = (yb - 10) * MT;
        stage_w<266, 268>(w_fu + off * 266, wlds);
        const float* fb   = f_fea + (size_t)b * 256 * HW + s;
        const float* yhf2 = y + (size_t)S2_HF2 * NPOS + p;
        const float* xf1  = xf + ((size_t)b * 20 + 10) * HW + s;
        float4 acc[MT];
#pragma unroll
        for (int o = 0; o < MT; ++o) acc[o] = make_float4(0.f, 0.f, 0.f, 0.f);
        auto gp = [&](int j) -> const float* {
            if (j < 256) return fb + (size_t)j * HW;
            int jj = j - 256, t = jj >> 1;
            return (jj & 1) ? xf1 + (size_t)t * HW
                            : yhf2 + (size_t)t * NPOS; };
        pipe_loop<69>(wstage, gp, [&](int k, float* bb) {
            if (k < 64) {
                float4 xs[4];
#pragma unroll
                for (int i = 0; i < 4; ++i) xs[i] = *(float4*)(bb + i * 256 + lane4);
#pragma unroll
                for (int o = 0; o < MT; ++o)
                    fma4x4(acc[o], ld4(wlds + o * 268 + k * 4), xs);
            } else {
                int t0 = (k - 64) * 2;
                float4 a0 = *(float4*)(bb + 0 * 256 + lane4);
                float4 b0 = *(float4*)(bb + 1 * 256 + lane4);
                float4 a1 = *(float4*)(bb + 2 * 256 + lane4);
                float4 b1 = *(float4*)(bb + 3 * 256 + lane4);
                int i0 = S2_HF2 - L2OFF + t0;
                float4 x0 = add4(bnrelu4(a0, ssc[i0], ssh[i0]), b0);
                float4 x1 = add4(bnrelu4(a1, ssc[i0 + 1], ssh[i0 + 1]), b1);
                int c0 = 256 + t0;
#pragma unroll
                for (int o = 0; o < MT; ++o) {
                    float2 w2 = *(const float2*)(wlds + o * 268 + c0);
                    fma1(acc[o], w2.x, x0);
                    fma1(acc[o], w2.y, x1);
                }
            }
        });
        finish(acc, y + (size_t)(S3_FU + off) * NPOS, p, sumA, sumqA, ST3_FU + off, red);
    }
}

// ---------------------------------------------------------------------------
__global__ void __launch_bounds__(256) final_kernel(const float* __restrict__ ws,
                                                    float* __restrict__ out)
{
    int g = blockIdx.x * 256 + threadIdx.x;
    int p = g * 4;
    int c = blockIdx.y;
    const float* sumA   = ws + (size_t)NSLOT * NPOS;
    const float* scaleA = sumA + 2 * NSTAT;
    const float* shiftA = scaleA + NSTAT;
    int slot, stat;
    if      (c < 70)  { slot = S3_PU  + c;         stat = ST3_PU  + c;         }
    else if (c < 100) { slot = S3_HU  + (c - 70);  stat = ST3_HU  + (c - 70);  }
    else if (c < 120) { slot = S3_FU  + (c - 100); stat = ST3_FU  + (c - 100); }
    else if (c < 150) { slot = S2_FD2 + (c - 120); stat = S2_FD2 + (c - 120);  }
    else              { slot = S2_HD2 + (c - 150); stat = S2_HD2 + (c - 150);  }
    float4 v = *(const float4*)(ws + (size_t)slot * NPOS + p);
    float sc = scaleA[stat], sh = shiftA[stat];
    v.x = fmaf(v.x, sc, sh); v.x = v.x > 0.f ? v.x : 0.f;
    v.y = fmaf(v.y, sc, sh); v.y = v.y > 0.f ? v.y : 0.f;
    v.z = fmaf(v.z, sc, sh); v.z = v.z > 0.f ? v.z : 0.f;
    v.w = fmaf(v.w, sc, sh); v.w = v.w > 0.f ? v.w : 0.f;
    int b = (p >= HW) ? 1 : 0;
    int s = p - b * HW;
    *(float4*)(out + ((size_t)b * 220 + c) * HW + s) = v;
}

// ---------------------------------------------------------------------------
extern "C" void kernel_launch(void* const* d_in, const int* in_sizes, int n_in,
                              void* d_out, int out_size, void* d_ws, size_t ws_size,
                              hipStream_t stream)
{
    const float* xp     = (const float*)d_in[0];
    const float* xh     = (const float*)d_in[1];
    const float* xf     = (const float*)d_in[2];
    const float* p_fea  = (const float*)d_in[3];
    const float* h_fea  = (const float*)d_in[4];
    const float* f_fea  = (const float*)d_in[5];
    const float* w_hf1  = (const float*)d_in[6];  const float* bn_hf1  = (const float*)d_in[7];
    const float* w_hf2  = (const float*)d_in[8];  const float* bn_hf2  = (const float*)d_in[9];
    const float* w_phu1 = (const float*)d_in[10]; const float* bn_phu1 = (const float*)d_in[11];
    const float* w_phu2 = (const float*)d_in[12]; const float* bn_phu2 = (const float*)d_in[13];
    const float* w_phl1 = (const float*)d_in[14]; const float* bn_phl1 = (const float*)d_in[15];
    const float* w_phl2 = (const float*)d_in[16]; const float* bn_phl2 = (const float*)d_in[17];
    const float* w_fd1  = (const float*)d_in[18]; const float* bn_fd1  = (const float*)d_in[19];
    const float* w_fd2  = (const float*)d_in[20]; const float* bn_fd2  = (const float*)d_in[21];
    const float* w_hd1  = (const float*)d_in[22]; const float* bn_hd1  = (const float*)d_in[23];
    const float* w_hd2  = (const float*)d_in[24]; const float* bn_hd2  = (const float*)d_in[25];
    const float* w_fu   = (const float*)d_in[26]; const float* bn_fu   = (const float*)d_in[27];
    const float* w_hu   = (const float*)d_in[28]; const float* bn_hu   = (const float*)d_in[29];
    const float* w_pu   = (const float*)d_in[30]; const float* bn_pu   = (const float*)d_in[31];

    float* ws  = (float*)d_ws;
    float* out = (float*)d_out;

    size_t need_bytes = ((size_t)NSLOT * NPOS + 4 * NSTAT) * sizeof(float);
    if (ws_size < need_bytes) return;

    hipMemsetAsync(ws + (size_t)NSLOT * NPOS, 0, 2 * NSTAT * sizeof(float), stream);

    dim3 blk(256);
    const int GX = NPOS / 1024;   // 72 x-blocks, 4 positions/thread
    stage1_kernel<<<dim3(GX, 16), blk, 0, stream>>>(xp, xh, xf, p_fea, h_fea,
                                                    w_hf1, w_fd1, w_phu1, w_phl1, w_hd1, ws);
    scale_kernel<<<1, 256, 0, stream>>>(1, bn_hf1, bn_hf2, bn_phu1, bn_phu2, bn_phl1, bn_phl2,
                                        bn_fd1, bn_fd2, bn_hd1, bn_hd2, bn_fu, bn_hu, bn_pu, ws);
    stage2_kernel<<<dim3(GX, 13), blk, 0, stream>>>(w_hf2, w_fd2, w_phu2, w_phl2, w_hd2, ws);
    scale_kernel<<<1, 256, 0, stream>>>(2, bn_hf1, bn_hf2, bn_phu1, bn_phu2, bn_phl1, bn_phl2,
                                        bn_fd1, bn_fd2, bn_hd1, bn_hd2, bn_fu, bn_hu, bn_pu, ws);
    stage3_kernel<<<dim3(GX, 12), blk, 0, stream>>>(xp, xh, xf, p_fea, h_fea, f_fea,
                                                    w_fu, w_hu, w_pu, ws);
    scale_kernel<<<1, 256, 0, stream>>>(3, bn_hf1, bn_hf2, bn_phu1, bn_phu2, bn_phl1, bn_phl2,
                                        bn_fd1, bn_fd2, bn_hd1, bn_hd2, bn_fu, bn_hu, bn_pu, ws);
    final_kernel<<<dim3(NPOS / 1024, 220), blk, 0, stream>>>(ws, out);
}

// Round 6
// 517.516 us; speedup vs baseline: 3.1277x; 1.2272x over previous
//
#include <hip/hip_runtime.h>
#include <stdint.h>

#define HW   36864      // 192*192
#define NPOS 73728      // B*HW, B=2
#define EPSV 1e-5f

// channel-slot layout in workspace (each slot = NPOS floats)
#define S1_HF1  0
#define S1_FD1  20
#define S1_PHU1 50
#define S1_PHL1 70
#define S1_HD1  90
#define S2_HF2  160
#define S2_FD2  170
#define S2_PHU2 200
#define S2_PHL2 210
#define S2_HD2  220
#define S3_FU   0       // reuse stage-1 slots (dead by stage 3)
#define S3_HU   20
#define S3_PU   50
#define ST3_FU  290
#define ST3_HU  310
#define ST3_PU  340
#define NSLOT 290
#define NSTAT 410
#define L2OFF 160

#define MT 10           // output channels per block

__device__ __forceinline__ float4 ld4(const float* p) { return *(const float4*)p; }

__device__ __forceinline__ float4 bnrelu4(float4 v, float sc, float sh) {
    float4 r;
    r.x = fmaf(v.x, sc, sh); r.y = fmaf(v.y, sc, sh);
    r.z = fmaf(v.z, sc, sh); r.w = fmaf(v.w, sc, sh);
    r.x = r.x > 0.f ? r.x : 0.f;
    r.y = r.y > 0.f ? r.y : 0.f;
    r.z = r.z > 0.f ? r.z : 0.f;
    r.w = r.w > 0.f ? r.w : 0.f;
    return r;
}

__device__ __forceinline__ float4 add4(float4 a, float4 b) {
    return make_float4(a.x + b.x, a.y + b.y, a.z + b.z, a.w + b.w);
}

// async 16B/lane global->LDS (zero VGPR in flight)
__device__ __forceinline__ void gld_lds16(const float* g, float* l)
{
    __builtin_amdgcn_global_load_lds(
        (const __attribute__((address_space(1))) uint32_t*)g,
        (__attribute__((address_space(3))) uint32_t*)l,
        16, 0, 0);
}

template<int CIN, int CINP>
__device__ __forceinline__ void stage_w(const float* __restrict__ w, float* wl)
{
    if (CIN == CINP) {
        for (int idx = threadIdx.x; idx < MT * CIN; idx += 256)
            wl[idx] = w[idx];
    } else {
        for (int idx = threadIdx.x; idx < MT * CIN; idx += 256) {
            int o = idx / CIN;
            int c = idx - o * CIN;
            wl[o * CINP + c] = w[idx];
        }
    }
    __syncthreads();
}

// 4 channels x 4 positions for one output channel, channel-ascending
__device__ __forceinline__ void fma4x4(float4& a, float4 w, const float4* buf)
{
    a.x = fmaf(w.x, buf[0].x, a.x); a.y = fmaf(w.x, buf[0].y, a.y);
    a.z = fmaf(w.x, buf[0].z, a.z); a.w = fmaf(w.x, buf[0].w, a.w);
    a.x = fmaf(w.y, buf[1].x, a.x); a.y = fmaf(w.y, buf[1].y, a.y);
    a.z = fmaf(w.y, buf[1].z, a.z); a.w = fmaf(w.y, buf[1].w, a.w);
    a.x = fmaf(w.z, buf[2].x, a.x); a.y = fmaf(w.z, buf[2].y, a.y);
    a.z = fmaf(w.z, buf[2].z, a.z); a.w = fmaf(w.z, buf[2].w, a.w);
    a.x = fmaf(w.w, buf[3].x, a.x); a.y = fmaf(w.w, buf[3].y, a.y);
    a.z = fmaf(w.w, buf[3].z, a.z); a.w = fmaf(w.w, buf[3].w, a.w);
}

__device__ __forceinline__ void fma1(float4& a, float w, float4 x)
{
    a.x = fmaf(w, x.x, a.x); a.y = fmaf(w, x.y, a.y);
    a.z = fmaf(w, x.z, a.z); a.w = fmaf(w, x.w, a.w);
}

// epilogue: y store + per-channel sum/sumsq reduction
__device__ __forceinline__ void finish(float4* acc, float* yo, int p,
                                       float* sumA, float* sumqA, int stat0,
                                       float* red)
{
#pragma unroll
    for (int o = 0; o < MT; ++o)
        *(float4*)(yo + (size_t)o * NPOS + p) = acc[o];
    int lane = threadIdx.x & 63;
    int wv_  = threadIdx.x >> 6;
#pragma unroll
    for (int o = 0; o < MT; ++o) {
        float s_ = (acc[o].x + acc[o].y) + (acc[o].z + acc[o].w);
        float q  = (acc[o].x * acc[o].x + acc[o].y * acc[o].y)
                 + (acc[o].z * acc[o].z + acc[o].w * acc[o].w);
#pragma unroll
        for (int i = 1; i < 64; i <<= 1) {
            s_ += __shfl_xor(s_, i, 64);
            q  += __shfl_xor(q, i, 64);
        }
        if (lane == 0) {
            red[(wv_ * MT + o) * 2]     = s_;
            red[(wv_ * MT + o) * 2 + 1] = q;
        }
    }
    __syncthreads();
    if (threadIdx.x < MT) {
        int o = threadIdx.x;
        float s_ = 0.f, q = 0.f;
#pragma unroll
        for (int k = 0; k < 4; ++k) {
            s_ += red[(k * MT + o) * 2];
            q  += red[(k * MT + o) * 2 + 1];
        }
        atomicAdd(&sumA[stat0 + o], s_);
        atomicAdd(&sumqA[stat0 + o], q);
    }
}

// ---------------------------------------------------------------------------
// Per-wave async staging pipeline, CONSUME-THEN-ISSUE (r5 failure fix).
// 2 buffers x 8 slots x 1KB per wave. Each iteration: wait -> consume chunk k
// from buffer cb -> reissue chunk k+2 into the SAME buffer (self-ordering:
// the overwrite cannot be hoisted above the reads). Any conservative
// compiler drain before consume now waits on loads issued one full consume
// (~700cy) earlier -> exposed stall ~ latency - 700 instead of full latency.
// cons(k, buf): consume full chunk k (slots 8k..8k+7). consr(buf): REM=4 tail.
// ---------------------------------------------------------------------------
template<int NFULL, int REM, class GP, class CONS, class CONSR>
__device__ __forceinline__ void pipe8(float* wstage, GP gp, CONS cons, CONSR consr)
{
    static_assert(NFULL >= 2, "pipe8 needs >=2 full chunks");
    static_assert(REM == 0 || REM == 4, "REM must be 0 or 4");
#pragma unroll
    for (int i = 0; i < 8; ++i) gld_lds16(gp(i), wstage + i * 256);
#pragma unroll
    for (int i = 0; i < 8; ++i) gld_lds16(gp(8 + i), wstage + 2048 + i * 256);
    int cb = 0;
#pragma unroll 1
    for (int k = 0; k + 2 < NFULL; ++k) {
        asm volatile("s_waitcnt vmcnt(8)" ::: "memory");   // chunk k landed
        float* bb = wstage + cb * 2048;
        cons(k, bb);
        asm volatile("s_waitcnt lgkmcnt(0)" ::: "memory"); // reads done before DMA overwrite
        int j0 = (k + 2) * 8;
#pragma unroll
        for (int i = 0; i < 8; ++i) gld_lds16(gp(j0 + i), bb + i * 256);
        cb ^= 1;
    }
    if constexpr (REM > 0) {
        asm volatile("s_waitcnt vmcnt(8)" ::: "memory");
        float* bb = wstage + cb * 2048;
        cons(NFULL - 2, bb);
        asm volatile("s_waitcnt lgkmcnt(0)" ::: "memory");
#pragma unroll
        for (int i = 0; i < 4; ++i) gld_lds16(gp(NFULL * 8 + i), bb + i * 256);
        cb ^= 1;
        asm volatile("s_waitcnt vmcnt(4)" ::: "memory");
        cons(NFULL - 1, wstage + cb * 2048);
        asm volatile("s_waitcnt vmcnt(0)" ::: "memory");
        consr(wstage + (cb ^ 1) * 2048);
    } else {
        asm volatile("s_waitcnt vmcnt(8)" ::: "memory");
        cons(NFULL - 2, wstage + cb * 2048);
        cb ^= 1;
        asm volatile("s_waitcnt vmcnt(0)" ::: "memory");
        cons(NFULL - 1, wstage + cb * 2048);
    }
}

// ---------------------------------------------------------------------------
// Register-path conv for small CIN (r3-proven).
// ---------------------------------------------------------------------------
template<int CIN, int CINP, class F>
__device__ __forceinline__ void conv4s(F fetch, const float* wl,
                                       float* __restrict__ y, int p,
                                       float* __restrict__ sumA,
                                       float* __restrict__ sumqA,
                                       int stat0, float* red)
{
    float4 acc[MT];
#pragma unroll
    for (int o = 0; o < MT; ++o) acc[o] = make_float4(0.f, 0.f, 0.f, 0.f);

    constexpr int CHUNK = 8;
    constexpr int MAIN = (CIN / CHUNK) * CHUNK;
    if (MAIN > 0) {
        float4 buf[CHUNK];
#pragma unroll
        for (int i = 0; i < CHUNK; ++i) buf[i] = fetch(i);
#pragma unroll 1
        for (int c0 = CHUNK; c0 < MAIN; c0 += CHUNK) {
            float4 nxt[CHUNK];
#pragma unroll
            for (int i = 0; i < CHUNK; ++i) nxt[i] = fetch(c0 + i);
            const float* wb = wl + (c0 - CHUNK);
#pragma unroll
            for (int o = 0; o < MT; ++o) {
                fma4x4(acc[o], ld4(wb + o * CINP), buf);
                fma4x4(acc[o], ld4(wb + o * CINP + 4), buf + 4);
            }
#pragma unroll
            for (int i = 0; i < CHUNK; ++i) buf[i] = nxt[i];
        }
        const float* wb = wl + (MAIN - CHUNK);
#pragma unroll
        for (int o = 0; o < MT; ++o) {
            fma4x4(acc[o], ld4(wb + o * CINP), buf);
            fma4x4(acc[o], ld4(wb + o * CINP + 4), buf + 4);
        }
    }
    constexpr int REM = CIN - MAIN;
    int ct = MAIN;
    if (REM >= 4) {
        float4 buf4[4];
#pragma unroll
        for (int i = 0; i < 4; ++i) buf4[i] = fetch(ct + i);
#pragma unroll
        for (int o = 0; o < MT; ++o)
            fma4x4(acc[o], ld4(wl + ct + o * CINP), buf4);
        ct += 4;
    }
#pragma unroll
    for (int c = ct; c < CIN; ++c) {
        float4 x = fetch(c);
#pragma unroll
        for (int o = 0; o < MT; ++o)
            fma1(acc[o], wl[o * CINP + c], x);
    }
    finish(acc, y, p, sumA, sumqA, stat0, red);
}

// ---------------------------------------------------------------------------
// Stage 1 (heavy-first): hd1(0..6) staged, fd1(7..9) staged, rest register
// ---------------------------------------------------------------------------
__global__ void __launch_bounds__(256, 2) stage1_kernel(
    const float* __restrict__ xp, const float* __restrict__ xh,
    const float* __restrict__ xf, const float* __restrict__ p_fea,
    const float* __restrict__ h_fea,
    const float* __restrict__ w_hf1, const float* __restrict__ w_fd1,
    const float* __restrict__ w_phu1, const float* __restrict__ w_phl1,
    const float* __restrict__ w_hd1, float* __restrict__ ws)
{
    __shared__ __align__(16) float stagebuf[4 * 4096];   // 64KB: 4 waves x 2 bufs x 8KB
    __shared__ __align__(16) float wlds[MT * 276];
    __shared__ float red[4 * MT * 2];
    int g = blockIdx.x * 256 + threadIdx.x;
    int p = g * 4;
    int b = (p >= HW) ? 1 : 0;
    int s = p - b * HW;
    float* y     = ws;
    float* sumA  = ws + (size_t)NSLOT * NPOS;
    float* sumqA = sumA + NSTAT;
    float* wstage = stagebuf + (threadIdx.x >> 6) * 4096;
    int lane4 = (threadIdx.x & 63) * 4;
    int yb = blockIdx.y;

    if (yb < 7) {            // hd1: [p_fea; xh1; xh2] (276): 34 full + rem4
        int off = yb * MT;
        stage_w<276, 276>(w_hd1 + off * 276, wlds);
        const float* pb = p_fea + (size_t)b * 256 * HW + s;
        const float* xb = xh + ((size_t)b * 30 + 10) * HW + s;
        float4 acc[MT];
#pragma unroll
        for (int o = 0; o < MT; ++o) acc[o] = make_float4(0.f, 0.f, 0.f, 0.f);
        auto gp = [&](int j) -> const float* {
            return (j < 256) ? pb + (size_t)j * HW : xb + (size_t)(j - 256) * HW; };
        pipe8<34, 4>(wstage, gp,
            [&](int k, float* bb) {
                float4 xs[8];
#pragma unroll
                for (int i = 0; i < 8; ++i) xs[i] = *(float4*)(bb + i * 256 + lane4);
#pragma unroll
                for (int o = 0; o < MT; ++o) {
                    fma4x4(acc[o], ld4(wlds + o * 276 + k * 8), xs);
                    fma4x4(acc[o], ld4(wlds + o * 276 + k * 8 + 4), xs + 4);
                }
            },
            [&](float* bb) {          // channels 272..275
                float4 xs[4];
#pragma unroll
                for (int i = 0; i < 4; ++i) xs[i] = *(float4*)(bb + i * 256 + lane4);
#pragma unroll
                for (int o = 0; o < MT; ++o)
                    fma4x4(acc[o], ld4(wlds + o * 276 + 272), xs);
            });
        finish(acc, y + (size_t)(S1_HD1 + off) * NPOS, p, sumA, sumqA, S1_HD1 + off, red);
    } else if (yb < 10) {    // fd1: [h_fea; xf1] (266): 33 full staged + 2 reg tail
        int off = (yb - 7) * MT;
        stage_w<266, 268>(w_fd1 + off * 266, wlds);
        const float* hb  = h_fea + (size_t)b * 256 * HW + s;
        const float* xf1 = xf + ((size_t)b * 20 + 10) * HW + s;
        float4 acc[MT];
#pragma unroll
        for (int o = 0; o < MT; ++o) acc[o] = make_float4(0.f, 0.f, 0.f, 0.f);
        auto gp = [&](int j) -> const float* {
            return (j < 256) ? hb + (size_t)j * HW : xf1 + (size_t)(j - 256) * HW; };
        pipe8<33, 0>(wstage, gp,
            [&](int k, float* bb) {
                float4 xs[8];
#pragma unroll
                for (int i = 0; i < 8; ++i) xs[i] = *(float4*)(bb + i * 256 + lane4);
#pragma unroll
                for (int o = 0; o < MT; ++o) {
                    fma4x4(acc[o], ld4(wlds + o * 268 + k * 8), xs);
                    fma4x4(acc[o], ld4(wlds + o * 268 + k * 8 + 4), xs + 4);
                }
            }, [](float*) {});
        float4 t0 = ld4(xf1 + (size_t)8 * HW);
        float4 t1 = ld4(xf1 + (size_t)9 * HW);
#pragma unroll
        for (int o = 0; o < MT; ++o) {
            fma1(acc[o], wlds[o * 268 + 264], t0);
            fma1(acc[o], wlds[o * 268 + 265], t1);
        }
        finish(acc, y + (size_t)(S1_FD1 + off) * NPOS, p, sumA, sumqA, S1_FD1 + off, red);
    } else if (yb < 12) {    // hf1 (20) register path
        int off = (yb - 10) * MT;
        stage_w<20, 20>(w_hf1 + off * 20, wlds);
        const float* xb = xh + ((size_t)b * 30 + 10) * HW + s;
        conv4s<20, 20>([&](int c) { return ld4(xb + c * HW); },
                       wlds, y + (size_t)(S1_HF1 + off) * NPOS, p,
                       sumA, sumqA, S1_HF1 + off, red);
    } else if (yb < 14) {    // phu1 (40) register path
        int off = (yb - 12) * MT;
        stage_w<40, 40>(w_phu1 + off * 40, wlds);
        const float* xb = xp + ((size_t)b * 70 + 10) * HW + s;
        conv4s<40, 40>([&](int c) { return ld4(xb + c * HW); },
                       wlds, y + (size_t)(S1_PHU1 + off) * NPOS, p,
                       sumA, sumqA, S1_PHU1 + off, red);
    } else {                 // phl1 (20) register path
        int off = (yb - 14) * MT;
        stage_w<20, 20>(w_phl1 + off * 20, wlds);
        const float* xb = xp + ((size_t)b * 70 + 50) * HW + s;
        conv4s<20, 20>([&](int c) { return ld4(xb + c * HW); },
                       wlds, y + (size_t)(S1_PHL1 + off) * NPOS, p,
                       sumA, sumqA, S1_PHL1 + off, red);
    }
}

// ---------------------------------------------------------------------------
__global__ void scale_kernel(int stage,
    const float* __restrict__ bn_hf1, const float* __restrict__ bn_hf2,
    const float* __restrict__ bn_phu1, const float* __restrict__ bn_phu2,
    const float* __restrict__ bn_phl1, const float* __restrict__ bn_phl2,
    const float* __restrict__ bn_fd1, const float* __restrict__ bn_fd2,
    const float* __restrict__ bn_hd1, const float* __restrict__ bn_hd2,
    const float* __restrict__ bn_fu, const float* __restrict__ bn_hu,
    const float* __restrict__ bn_pu, float* __restrict__ ws)
{
    int t = threadIdx.x;
    float* sumA   = ws + (size_t)NSLOT * NPOS;
    float* sumqA  = sumA + NSTAT;
    float* scaleA = sumqA + NSTAT;
    float* shiftA = scaleA + NSTAT;
    int stat, local, co;
    const float* bn;
    if (stage == 1) {
        if (t >= 160) return;
        stat = t;
        if      (t < 20) { bn = bn_hf1;  local = t;      co = 20; }
        else if (t < 50) { bn = bn_fd1;  local = t - 20; co = 30; }
        else if (t < 70) { bn = bn_phu1; local = t - 50; co = 20; }
        else if (t < 90) { bn = bn_phl1; local = t - 70; co = 20; }
        else             { bn = bn_hd1;  local = t - 90; co = 70; }
    } else if (stage == 2) {
        if (t >= 130) return;
        stat = 160 + t;
        if      (t < 10) { bn = bn_hf2;  local = t;      co = 10; }
        else if (t < 40) { bn = bn_fd2;  local = t - 10; co = 30; }
        else if (t < 50) { bn = bn_phu2; local = t - 40; co = 10; }
        else if (t < 60) { bn = bn_phl2; local = t - 50; co = 10; }
        else             { bn = bn_hd2;  local = t - 60; co = 70; }
    } else {
        if (t >= 120) return;
        stat = 290 + t;
        if      (t < 20) { bn = bn_fu; local = t;      co = 20; }
        else if (t < 50) { bn = bn_hu; local = t - 20; co = 30; }
        else             { bn = bn_pu; local = t - 50; co = 70; }
    }
    float n  = (float)NPOS;
    float m  = sumA[stat] / n;
    float v  = sumqA[stat] / n - m * m;
    float g  = bn[local];
    float bt = bn[co + local];
    float sc = g * rsqrtf(v + EPSV);
    scaleA[stat] = sc;
    shiftA[stat] = bt - m * sc;
}

// ---------------------------------------------------------------------------
// Stage 2 (heavy-first): hd2(0..6) staged, fd2(7..9)/hf2(10)/phu2(11)/phl2(12)
// ---------------------------------------------------------------------------
__global__ void __launch_bounds__(256, 2) stage2_kernel(
    const float* __restrict__ w_hf2, const float* __restrict__ w_fd2,
    const float* __restrict__ w_phu2, const float* __restrict__ w_phl2,
    const float* __restrict__ w_hd2, float* __restrict__ ws)
{
    __shared__ __align__(16) float stagebuf[4 * 4096];
    __shared__ __align__(16) float wlds[MT * 72];
    __shared__ float red[4 * MT * 2];
    __shared__ float ssc[160], ssh[160];
    int g = blockIdx.x * 256 + threadIdx.x;
    int p = g * 4;
    float* y     = ws;
    float* sumA  = ws + (size_t)NSLOT * NPOS;
    float* sumqA = sumA + NSTAT;
    const float* scaleA = sumqA + NSTAT;
    const float* shiftA = scaleA + NSTAT;
    float* wstage = stagebuf + (threadIdx.x >> 6) * 4096;
    int lane4 = (threadIdx.x & 63) * 4;

    for (int i = threadIdx.x; i < 160; i += 256) { ssc[i] = scaleA[i]; ssh[i] = shiftA[i]; }
    int yb = blockIdx.y;

    if (yb < 7) {            // hd2: hd1(70): 8 full + rem4 staged + 2 reg tail
        int off = yb * MT;
        stage_w<70, 72>(w_hd2 + off * 70, wlds);
        const float* src = y + (size_t)S1_HD1 * NPOS + p;
        float4 acc[MT];
#pragma unroll
        for (int o = 0; o < MT; ++o) acc[o] = make_float4(0.f, 0.f, 0.f, 0.f);
        auto gp = [&](int j) -> const float* { return src + (size_t)j * NPOS; };
        pipe8<8, 4>(wstage, gp,
            [&](int k, float* bb) {
                float4 xs[8];
#pragma unroll
                for (int i = 0; i < 8; ++i) {
                    int c = k * 8 + i;
                    float4 v = *(float4*)(bb + i * 256 + lane4);
                    xs[i] = bnrelu4(v, ssc[S1_HD1 + c], ssh[S1_HD1 + c]);
                }
#pragma unroll
                for (int o = 0; o < MT; ++o) {
                    fma4x4(acc[o], ld4(wlds + o * 72 + k * 8), xs);
                    fma4x4(acc[o], ld4(wlds + o * 72 + k * 8 + 4), xs + 4);
                }
            },
            [&](float* bb) {          // channels 64..67
                float4 xs[4];
#pragma unroll
                for (int i = 0; i < 4; ++i) {
                    int c = 64 + i;
                    float4 v = *(float4*)(bb + i * 256 + lane4);
                    xs[i] = bnrelu4(v, ssc[S1_HD1 + c], ssh[S1_HD1 + c]);
                }
#pragma unroll
                for (int o = 0; o < MT; ++o)
                    fma4x4(acc[o], ld4(wlds + o * 72 + 64), xs);
            });
        float4 t0 = bnrelu4(ld4(src + (size_t)68 * NPOS), ssc[S1_HD1 + 68], ssh[S1_HD1 + 68]);
        float4 t1 = bnrelu4(ld4(src + (size_t)69 * NPOS), ssc[S1_HD1 + 69], ssh[S1_HD1 + 69]);
#pragma unroll
        for (int o = 0; o < MT; ++o) {
            fma1(acc[o], wlds[o * 72 + 68], t0);
            fma1(acc[o], wlds[o * 72 + 69], t1);
        }
        finish(acc, y + (size_t)(S2_HD2 + off) * NPOS, p, sumA, sumqA, S2_HD2 + off, red);
    } else if (yb < 10) {    // fd2 (30) register path
        int off = (yb - 7) * MT;
        stage_w<30, 32>(w_fd2 + off * 30, wlds);
        const float* src = y + (size_t)S1_FD1 * NPOS + p;
        conv4s<30, 32>([&](int c) {
            return bnrelu4(ld4(src + (size_t)c * NPOS), ssc[S1_FD1 + c], ssh[S1_FD1 + c]); },
            wlds, y + (size_t)(S2_FD2 + off) * NPOS, p, sumA, sumqA, S2_FD2 + off, red);
    } else if (yb == 10) {   // hf2
        stage_w<20, 20>(w_hf2, wlds);
        const float* src = y + (size_t)S1_HF1 * NPOS + p;
        conv4s<20, 20>([&](int c) {
            return bnrelu4(ld4(src + (size_t)c * NPOS), ssc[S1_HF1 + c], ssh[S1_HF1 + c]); },
            wlds, y + (size_t)S2_HF2 * NPOS, p, sumA, sumqA, S2_HF2, red);
    } else if (yb == 11) {   // phu2
        stage_w<20, 20>(w_phu2, wlds);
        const float* src = y + (size_t)S1_PHU1 * NPOS + p;
        conv4s<20, 20>([&](int c) {
            return bnrelu4(ld4(src + (size_t)c * NPOS), ssc[S1_PHU1 + c], ssh[S1_PHU1 + c]); },
            wlds, y + (size_t)S2_PHU2 * NPOS, p, sumA, sumqA, S2_PHU2, red);
    } else {                 // phl2
        stage_w<20, 20>(w_phl2, wlds);
        const float* src = y + (size_t)S1_PHL1 * NPOS + p;
        conv4s<20, 20>([&](int c) {
            return bnrelu4(ld4(src + (size_t)c * NPOS), ssc[S1_PHL1 + c], ssh[S1_PHL1 + c]); },
            wlds, y + (size_t)S2_PHL2 * NPOS, p, sumA, sumqA, S2_PHL2, red);
    }
}

// ---------------------------------------------------------------------------
// Stage 3 (heavy-first): pu(0..6), hu(7..9), fu(10,11) — all staged.
// Composite channels staged as interleaved raw streams, combined post-LDS.
// ---------------------------------------------------------------------------
__global__ void __launch_bounds__(256, 2) stage3_kernel(
    const float* __restrict__ xp, const float* __restrict__ xh,
    const float* __restrict__ xf, const float* __restrict__ p_fea,
    const float* __restrict__ h_fea, const float* __restrict__ f_fea,
    const float* __restrict__ w_fu, const float* __restrict__ w_hu,
    const float* __restrict__ w_pu, float* __restrict__ ws)
{
    __shared__ __align__(16) float stagebuf[4 * 4096];
    __shared__ __align__(16) float wlds[MT * 316];
    __shared__ float red[4 * MT * 2];
    __shared__ float ssc[130], ssh[130];
    int g = blockIdx.x * 256 + threadIdx.x;
    int p = g * 4;
    int b = (p >= HW) ? 1 : 0;
    int s = p - b * HW;
    float* y     = ws;
    float* sumA  = ws + (size_t)NSLOT * NPOS;
    float* sumqA = sumA + NSTAT;
    const float* scaleA = sumqA + NSTAT;
    const float* shiftA = scaleA + NSTAT;
    float* wstage = stagebuf + (threadIdx.x >> 6) * 4096;
    int lane4 = (threadIdx.x & 63) * 4;

    for (int i = threadIdx.x; i < 130; i += 256) {
        ssc[i] = scaleA[L2OFF + i]; ssh[i] = shiftA[L2OFF + i];
    }
    int yb = blockIdx.y;

    if (yb < 7) {            // pu (316): 256 pure + 60 pairs = 376 slots = 47 full
        int off = yb * MT;
        stage_w<316, 316>(w_pu + off * 316, wlds);
        const float* pb   = p_fea + (size_t)b * 256 * HW + s;
        const float* yhd2 = y + (size_t)S2_HD2 * NPOS + p;
        const float* xpb  = xp + ((size_t)b * 70 + 10) * HW + s;
        float4 acc[MT];
#pragma unroll
        for (int o = 0; o < MT; ++o) acc[o] = make_float4(0.f, 0.f, 0.f, 0.f);
        auto gp = [&](int j) -> const float* {
            if (j < 256) return pb + (size_t)j * HW;
            int jj = j - 256, t = jj >> 1;
            return (jj & 1) ? xpb + (size_t)t * HW
                            : yhd2 + (size_t)(10 + t) * NPOS; };
        pipe8<47, 0>(wstage, gp,
            [&](int k, float* bb) {
                if (k < 32) {
                    float4 xs[8];
#pragma unroll
                    for (int i = 0; i < 8; ++i) xs[i] = *(float4*)(bb + i * 256 + lane4);
#pragma unroll
                    for (int o = 0; o < MT; ++o) {
                        fma4x4(acc[o], ld4(wlds + o * 316 + k * 8), xs);
                        fma4x4(acc[o], ld4(wlds + o * 316 + k * 8 + 4), xs + 4);
                    }
                } else {
                    int t0 = (k - 32) * 4;          // pair base
                    float4 x[4];
#pragma unroll
                    for (int q = 0; q < 4; ++q) {
                        float4 a = *(float4*)(bb + (2 * q) * 256 + lane4);
                        float4 bx = *(float4*)(bb + (2 * q + 1) * 256 + lane4);
                        int ia = S2_HD2 - L2OFF + 10 + t0 + q;
                        x[q] = add4(bnrelu4(a, ssc[ia], ssh[ia]), bx);
                    }
                    int c0 = 256 + t0;
#pragma unroll
                    for (int o = 0; o < MT; ++o)
                        fma4x4(acc[o], ld4(wlds + o * 316 + c0), x);
                }
            }, [](float*) {});
        finish(acc, y + (size_t)(S3_PU + off) * NPOS, p, sumA, sumqA, ST3_PU + off, red);
    } else if (yb < 10) {    // hu (276): 256 pure + 20 quads = 336 slots = 42 full
        int off = (yb - 7) * MT;
        stage_w<276, 276>(w_hu + off * 276, wlds);
        const float* hb    = h_fea + (size_t)b * 256 * HW + s;
        const float* yphu2 = y + (size_t)S2_PHU2 * NPOS + p;
        const float* yphl2 = y + (size_t)S2_PHL2 * NPOS + p;
        const float* yfd2  = y + (size_t)S2_FD2 * NPOS + p;
        const float* xh1b  = xh + ((size_t)b * 30 + 10) * HW + s;
        float4 acc[MT];
#pragma unroll
        for (int o = 0; o < MT; ++o) acc[o] = make_float4(0.f, 0.f, 0.f, 0.f);
        auto gp = [&](int j) -> const float* {
            if (j < 256) return hb + (size_t)j * HW;
            int jj = j - 256, t = jj >> 2, r = jj & 3;
            if (r == 0) return (t < 10) ? yphu2 + (size_t)t * NPOS
                                        : yphl2 + (size_t)(t - 10) * NPOS;
            if (r == 1) return yfd2 + (size_t)(10 + t) * NPOS;
            return xh1b + (size_t)t * HW;      // r==2 real, r==3 pad
        };
        pipe8<42, 0>(wstage, gp,
            [&](int k, float* bb) {
                if (k < 32) {
                    float4 xs[8];
#pragma unroll
                    for (int i = 0; i < 8; ++i) xs[i] = *(float4*)(bb + i * 256 + lane4);
#pragma unroll
                    for (int o = 0; o < MT; ++o) {
                        fma4x4(acc[o], ld4(wlds + o * 276 + k * 8), xs);
                        fma4x4(acc[o], ld4(wlds + o * 276 + k * 8 + 4), xs + 4);
                    }
                } else {
                    int t = (k - 32) * 2;           // quad base
                    float4 x2[2];
#pragma unroll
                    for (int q = 0; q < 2; ++q) {
                        float4 A = *(float4*)(bb + (4 * q) * 256 + lane4);
                        float4 F = *(float4*)(bb + (4 * q + 1) * 256 + lane4);
                        float4 R = *(float4*)(bb + (4 * q + 2) * 256 + lane4);
                        int tq = t + q;
                        int ia = (tq < 10) ? (S2_PHU2 - L2OFF + tq) : (S2_PHL2 - L2OFF + tq - 10);
                        int iff = S2_FD2 - L2OFF + 10 + tq;
                        float4 a = bnrelu4(A, ssc[ia], ssh[ia]);
                        float4 f = bnrelu4(F, ssc[iff], ssh[iff]);
                        x2[q] = make_float4(R.x + a.x + f.x, R.y + a.y + f.y,
                                            R.z + a.z + f.z, R.w + a.w + f.w);
                    }
                    int c = 256 + t;
#pragma unroll
                    for (int o = 0; o < MT; ++o) {
                        float2 w2 = *(const float2*)(wlds + o * 276 + c);
                        fma1(acc[o], w2.x, x2[0]);
                        fma1(acc[o], w2.y, x2[1]);
                    }
                }
            }, [](float*) {});
        finish(acc, y + (size_t)(S3_HU + off) * NPOS, p, sumA, sumqA, ST3_HU + off, red);
    } else {                 // fu (266): 256 pure + 10 pairs = 276 slots = 34 full + rem4
        int off = (yb - 10) * MT;
        stage_w<266, 268>(w_fu + off * 266, wlds);
        const float* fb   = f_fea + (size_t)b * 256 * HW + s;
        const float* yhf2 = y + (size_t)S2_HF2 * NPOS + p;
        const float* xf1  = xf + ((size_t)b * 20 + 10) * HW + s;
        float4 acc[MT];
#pragma unroll
        for (int o = 0; o < MT; ++o) acc[o] = make_float4(0.f, 0.f, 0.f, 0.f);
        auto gp = [&](int j) -> const float* {
            if (j < 256) return fb + (size_t)j * HW;
            int jj = j - 256, t = jj >> 1;
            return (jj & 1) ? xf1 + (size_t)t * HW
                            : yhf2 + (size_t)t * NPOS; };
        pipe8<34, 4>(wstage, gp,
            [&](int k, float* bb) {
                if (k < 32) {
                    float4 xs[8];
#pragma unroll
                    for (int i = 0; i < 8; ++i) xs[i] = *(float4*)(bb + i * 256 + lane4);
#pragma unroll
                    for (int o = 0; o < MT; ++o) {
                        fma4x4(acc[o], ld4(wlds + o * 268 + k * 8), xs);
                        fma4x4(acc[o], ld4(wlds + o * 268 + k * 8 + 4), xs + 4);
                    }
                } else {
                    int t0 = (k - 32) * 4;          // pair base
                    float4 x[4];
#pragma unroll
                    for (int q = 0; q < 4; ++q) {
                        float4 a = *(float4*)(bb + (2 * q) * 256 + lane4);
                        float4 bx = *(float4*)(bb + (2 * q + 1) * 256 + lane4);
                        int i0 = S2_HF2 - L2OFF + t0 + q;
                        x[q] = add4(bnrelu4(a, ssc[i0], ssh[i0]), bx);
                    }
                    int c0 = 256 + t0;
#pragma unroll
                    for (int o = 0; o < MT; ++o)
                        fma4x4(acc[o], ld4(wlds + o * 268 + c0), x);
                }
            },
            [&](float* bb) {          // pairs 8,9 -> channels 264,265
                float4 a0 = *(float4*)(bb + 0 * 256 + lane4);
                float4 b0 = *(float4*)(bb + 1 * 256 + lane4);
                float4 a1 = *(float4*)(bb + 2 * 256 + lane4);
                float4 b1 = *(float4*)(bb + 3 * 256 + lane4);
                int i0 = S2_HF2 - L2OFF + 8;
                float4 x0 = add4(bnrelu4(a0, ssc[i0], ssh[i0]), b0);
                float4 x1 = add4(bnrelu4(a1, ssc[i0 + 1], ssh[i0 + 1]), b1);
#pragma unroll
                for (int o = 0; o < MT; ++o) {
                    float2 w2 = *(const float2*)(wlds + o * 268 + 264);
                    fma1(acc[o], w2.x, x0);
                    fma1(acc[o], w2.y, x1);
                }
            });
        finish(acc, y + (size_t)(S3_FU + off) * NPOS, p, sumA, sumqA, ST3_FU + off, red);
    }
}

// ---------------------------------------------------------------------------
__global__ void __launch_bounds__(256) final_kernel(const float* __restrict__ ws,
                                                    float* __restrict__ out)
{
    int g = blockIdx.x * 256 + threadIdx.x;
    int p = g * 4;
    int c = blockIdx.y;
    const float* sumA   = ws + (size_t)NSLOT * NPOS;
    const float* scaleA = sumA + 2 * NSTAT;
    const float* shiftA = scaleA + NSTAT;
    int slot, stat;
    if      (c < 70)  { slot = S3_PU  + c;         stat = ST3_PU  + c;         }
    else if (c < 100) { slot = S3_HU  + (c - 70);  stat = ST3_HU  + (c - 70);  }
    else if (c < 120) { slot = S3_FU  + (c - 100); stat = ST3_FU  + (c - 100); }
    else if (c < 150) { slot = S2_FD2 + (c - 120); stat = S2_FD2 + (c - 120);  }
    else              { slot = S2_HD2 + (c - 150); stat = S2_HD2 + (c - 150);  }
    float4 v = *(const float4*)(ws + (size_t)slot * NPOS + p);
    float sc = scaleA[stat], sh = shiftA[stat];
    v.x = fmaf(v.x, sc, sh); v.x = v.x > 0.f ? v.x : 0.f;
    v.y = fmaf(v.y, sc, sh); v.y = v.y > 0.f ? v.y : 0.f;
    v.z = fmaf(v.z, sc, sh); v.z = v.z > 0.f ? v.z : 0.f;
    v.w = fmaf(v.w, sc, sh); v.w = v.w > 0.f ? v.w : 0.f;
    int b = (p >= HW) ? 1 : 0;
    int s = p - b * HW;
    *(float4*)(out + ((size_t)b * 220 + c) * HW + s) = v;
}

// ---------------------------------------------------------------------------
extern "C" void kernel_launch(void* const* d_in, const int* in_sizes, int n_in,
                              void* d_out, int out_size, void* d_ws, size_t ws_size,
                              hipStream_t stream)
{
    const float* xp     = (const float*)d_in[0];
    const float* xh     = (const float*)d_in[1];
    const float* xf     = (const float*)d_in[2];
    const float* p_fea  = (const float*)d_in[3];
    const float* h_fea  = (const float*)d_in[4];
    const float* f_fea  = (const float*)d_in[5];
    const float* w_hf1  = (const float*)d_in[6];  const float* bn_hf1  = (const float*)d_in[7];
    const float* w_hf2  = (const float*)d_in[8];  const float* bn_hf2  = (const float*)d_in[9];
    const float* w_phu1 = (const float*)d_in[10]; const float* bn_phu1 = (const float*)d_in[11];
    const float* w_phu2 = (const float*)d_in[12]; const float* bn_phu2 = (const float*)d_in[13];
    const float* w_phl1 = (const float*)d_in[14]; const float* bn_phl1 = (const float*)d_in[15];
    const float* w_phl2 = (const float*)d_in[16]; const float* bn_phl2 = (const float*)d_in[17];
    const float* w_fd1  = (const float*)d_in[18]; const float* bn_fd1  = (const float*)d_in[19];
    const float* w_fd2  = (const float*)d_in[20]; const float* bn_fd2  = (const float*)d_in[21];
    const float* w_hd1  = (const float*)d_in[22]; const float* bn_hd1  = (const float*)d_in[23];
    const float* w_hd2  = (const float*)d_in[24]; const float* bn_hd2  = (const float*)d_in[25];
    const float* w_fu   = (const float*)d_in[26]; const float* bn_fu   = (const float*)d_in[27];
    const float* w_hu   = (const float*)d_in[28]; const float* bn_hu   = (const float*)d_in[29];
    const float* w_pu   = (const float*)d_in[30]; const float* bn_pu   = (const float*)d_in[31];

    float* ws  = (float*)d_ws;
    float* out = (float*)d_out;

    size_t need_bytes = ((size_t)NSLOT * NPOS + 4 * NSTAT) * sizeof(float);
    if (ws_size < need_bytes) return;

    hipMemsetAsync(ws + (size_t)NSLOT * NPOS, 0, 2 * NSTAT * sizeof(float), stream);

    dim3 blk(256);
    const int GX = NPOS / 1024;   // 72 x-blocks, 4 positions/thread
    stage1_kernel<<<dim3(GX, 16), blk, 0, stream>>>(xp, xh, xf, p_fea, h_fea,
                                                    w_hf1, w_fd1, w_phu1, w_phl1, w_hd1, ws);
    scale_kernel<<<1, 256, 0, stream>>>(1, bn_hf1, bn_hf2, bn_phu1, bn_phu2, bn_phl1, bn_phl2,
                                        bn_fd1, bn_fd2, bn_hd1, bn_hd2, bn_fu, bn_hu, bn_pu, ws);
    stage2_kernel<<<dim3(GX, 13), blk, 0, stream>>>(w_hf2, w_fd2, w_phu2, w_phl2, w_hd2, ws);
    scale_kernel<<<1, 256, 0, stream>>>(2, bn_hf1, bn_hf2, bn_phu1, bn_phu2, bn_phl1, bn_phl2,
                                        bn_fd1, bn_fd2, bn_hd1, bn_hd2, bn_fu, bn_hu, bn_pu, ws);
    stage3_kernel<<<dim3(GX, 12), blk, 0, stream>>>(xp, xh, xf, p_fea, h_fea, f_fea,
                                                    w_fu, w_hu, w_pu, ws);
    scale_kernel<<<1, 256, 0, stream>>>(3, bn_hf1, bn_hf2, bn_phu1, bn_phu2, bn_phl1, bn_phl2,
                                        bn_fd1, bn_fd2, bn_hd1, bn_hd2, bn_fu, bn_hu, bn_pu, ws);
    final_kernel<<<dim3(NPOS / 1024, 220), blk, 0, stream>>>(ws, out);
}

// Round 7
// 504.874 us; speedup vs baseline: 3.2060x; 1.0250x over previous
//
#include <hip/hip_runtime.h>
#include <stdint.h>

#define HW   36864      // 192*192
#define NPOS 73728      // B*HW, B=2
#define EPSV 1e-5f

// channel-slot layout in workspace (each slot = NPOS floats)
#define S1_HF1  0
#define S1_FD1  20
#define S1_PHU1 50
#define S1_PHL1 70
#define S1_HD1  90
#define S2_HF2  160
#define S2_FD2  170
#define S2_PHU2 200
#define S2_PHL2 210
#define S2_HD2  220
#define S3_FU   0       // reuse stage-1 slots (dead by stage 3)
#define S3_HU   20
#define S3_PU   50
#define ST3_FU  290
#define ST3_HU  310
#define ST3_PU  340
#define NSLOT 290
#define NSTAT 410
#define L2OFF 160

__device__ __forceinline__ float4 ld4(const float* p) { return *(const float4*)p; }

__device__ __forceinline__ float4 bnrelu4(float4 v, float sc, float sh) {
    float4 r;
    r.x = fmaf(v.x, sc, sh); r.y = fmaf(v.y, sc, sh);
    r.z = fmaf(v.z, sc, sh); r.w = fmaf(v.w, sc, sh);
    r.x = r.x > 0.f ? r.x : 0.f;
    r.y = r.y > 0.f ? r.y : 0.f;
    r.z = r.z > 0.f ? r.z : 0.f;
    r.w = r.w > 0.f ? r.w : 0.f;
    return r;
}

__device__ __forceinline__ float4 add4(float4 a, float4 b) {
    return make_float4(a.x + b.x, a.y + b.y, a.z + b.z, a.w + b.w);
}

// async 16B/lane global->LDS (zero VGPR in flight)
__device__ __forceinline__ void gld_lds16(const float* g, float* l)
{
    __builtin_amdgcn_global_load_lds(
        (const __attribute__((address_space(1))) uint32_t*)g,
        (__attribute__((address_space(3))) uint32_t*)l,
        16, 0, 0);
}

template<int CIN, int CINP, int MTP>
__device__ __forceinline__ void stage_w(const float* __restrict__ w, float* wl)
{
    if (CIN == CINP) {
        for (int idx = threadIdx.x; idx < MTP * CIN; idx += 256)
            wl[idx] = w[idx];
    } else {
        for (int idx = threadIdx.x; idx < MTP * CIN; idx += 256) {
            int o = idx / CIN;
            int c = idx - o * CIN;
            wl[o * CINP + c] = w[idx];
        }
    }
    __syncthreads();
}

// 4 channels x 4 positions for one output channel, channel-ascending
__device__ __forceinline__ void fma4x4(float4& a, float4 w, const float4* buf)
{
    a.x = fmaf(w.x, buf[0].x, a.x); a.y = fmaf(w.x, buf[0].y, a.y);
    a.z = fmaf(w.x, buf[0].z, a.z); a.w = fmaf(w.x, buf[0].w, a.w);
    a.x = fmaf(w.y, buf[1].x, a.x); a.y = fmaf(w.y, buf[1].y, a.y);
    a.z = fmaf(w.y, buf[1].z, a.z); a.w = fmaf(w.y, buf[1].w, a.w);
    a.x = fmaf(w.z, buf[2].x, a.x); a.y = fmaf(w.z, buf[2].y, a.y);
    a.z = fmaf(w.z, buf[2].z, a.z); a.w = fmaf(w.z, buf[2].w, a.w);
    a.x = fmaf(w.w, buf[3].x, a.x); a.y = fmaf(w.w, buf[3].y, a.y);
    a.z = fmaf(w.w, buf[3].z, a.z); a.w = fmaf(w.w, buf[3].w, a.w);
}

__device__ __forceinline__ void fma1(float4& a, float w, float4 x)
{
    a.x = fmaf(w, x.x, a.x); a.y = fmaf(w, x.y, a.y);
    a.z = fmaf(w, x.z, a.z); a.w = fmaf(w, x.w, a.w);
}

// epilogue: y store + per-channel sum/sumsq reduction
template<int MTP>
__device__ __forceinline__ void finish(float4* acc, float* yo, int p,
                                       float* sumA, float* sumqA, int stat0,
                                       float* red)
{
#pragma unroll
    for (int o = 0; o < MTP; ++o)
        *(float4*)(yo + (size_t)o * NPOS + p) = acc[o];
    int lane = threadIdx.x & 63;
    int wv_  = threadIdx.x >> 6;
#pragma unroll
    for (int o = 0; o < MTP; ++o) {
        float s_ = (acc[o].x + acc[o].y) + (acc[o].z + acc[o].w);
        float q  = (acc[o].x * acc[o].x + acc[o].y * acc[o].y)
                 + (acc[o].z * acc[o].z + acc[o].w * acc[o].w);
#pragma unroll
        for (int i = 1; i < 64; i <<= 1) {
            s_ += __shfl_xor(s_, i, 64);
            q  += __shfl_xor(q, i, 64);
        }
        if (lane == 0) {
            red[(wv_ * MTP + o) * 2]     = s_;
            red[(wv_ * MTP + o) * 2 + 1] = q;
        }
    }
    __syncthreads();
    if (threadIdx.x < MTP) {
        int o = threadIdx.x;
        float s_ = 0.f, q = 0.f;
#pragma unroll
        for (int k = 0; k < 4; ++k) {
            s_ += red[(k * MTP + o) * 2];
            q  += red[(k * MTP + o) * 2 + 1];
        }
        atomicAdd(&sumA[stat0 + o], s_);
        atomicAdd(&sumqA[stat0 + o], q);
    }
}

// ---------------------------------------------------------------------------
// Per-wave async staging pipeline, consume-then-issue (r6-proven), chunk=4.
// 2 buffers x 4 slots x 1KB per wave (8KB/wave, 32KB/block) -> 3-4 blocks/CU.
// ---------------------------------------------------------------------------
template<int NFULL, class GP, class CONS>
__device__ __forceinline__ void pipe4(float* wstage, GP gp, CONS cons)
{
    static_assert(NFULL >= 2, "pipe4 needs >=2 chunks");
#pragma unroll
    for (int i = 0; i < 4; ++i) gld_lds16(gp(i), wstage + i * 256);
#pragma unroll
    for (int i = 0; i < 4; ++i) gld_lds16(gp(4 + i), wstage + 1024 + i * 256);
    int cb = 0;
#pragma unroll 1
    for (int k = 0; k + 2 < NFULL; ++k) {
        asm volatile("s_waitcnt vmcnt(4)" ::: "memory");   // chunk k landed
        float* bb = wstage + cb * 1024;
        cons(k, bb);
        asm volatile("s_waitcnt lgkmcnt(0)" ::: "memory"); // reads done before DMA overwrite
        int j0 = (k + 2) * 4;
#pragma unroll
        for (int i = 0; i < 4; ++i) gld_lds16(gp(j0 + i), bb + i * 256);
        cb ^= 1;
    }
    asm volatile("s_waitcnt vmcnt(4)" ::: "memory");
    cons(NFULL - 2, wstage + cb * 1024);
    cb ^= 1;
    asm volatile("s_waitcnt vmcnt(0)" ::: "memory");
    cons(NFULL - 1, wstage + cb * 1024);
}

// ---------------------------------------------------------------------------
// Register-path conv for small CIN (r3-proven, CHUNK=8 prefetch).
// ---------------------------------------------------------------------------
template<int CIN, int CINP, int MTP, class F>
__device__ __forceinline__ void conv4s(F fetch, const float* wl,
                                       float* __restrict__ y, int p,
                                       float* __restrict__ sumA,
                                       float* __restrict__ sumqA,
                                       int stat0, float* red)
{
    float4 acc[MTP];
#pragma unroll
    for (int o = 0; o < MTP; ++o) acc[o] = make_float4(0.f, 0.f, 0.f, 0.f);

    constexpr int CHUNK = 8;
    constexpr int MAIN = (CIN / CHUNK) * CHUNK;
    if (MAIN > 0) {
        float4 buf[CHUNK];
#pragma unroll
        for (int i = 0; i < CHUNK; ++i) buf[i] = fetch(i);
#pragma unroll 1
        for (int c0 = CHUNK; c0 < MAIN; c0 += CHUNK) {
            float4 nxt[CHUNK];
#pragma unroll
            for (int i = 0; i < CHUNK; ++i) nxt[i] = fetch(c0 + i);
            const float* wb = wl + (c0 - CHUNK);
#pragma unroll
            for (int o = 0; o < MTP; ++o) {
                fma4x4(acc[o], ld4(wb + o * CINP), buf);
                fma4x4(acc[o], ld4(wb + o * CINP + 4), buf + 4);
            }
#pragma unroll
            for (int i = 0; i < CHUNK; ++i) buf[i] = nxt[i];
        }
        const float* wb = wl + (MAIN - CHUNK);
#pragma unroll
        for (int o = 0; o < MTP; ++o) {
            fma4x4(acc[o], ld4(wb + o * CINP), buf);
            fma4x4(acc[o], ld4(wb + o * CINP + 4), buf + 4);
        }
    }
    constexpr int REM = CIN - MAIN;
    int ct = MAIN;
    if (REM >= 4) {
        float4 buf4[4];
#pragma unroll
        for (int i = 0; i < 4; ++i) buf4[i] = fetch(ct + i);
#pragma unroll
        for (int o = 0; o < MTP; ++o)
            fma4x4(acc[o], ld4(wl + ct + o * CINP), buf4);
        ct += 4;
    }
#pragma unroll
    for (int c = ct; c < CIN; ++c) {
        float4 x = fetch(c);
#pragma unroll
        for (int o = 0; o < MTP; ++o)
            fma1(acc[o], wl[o * CINP + c], x);
    }
    finish<MTP>(acc, y, p, sumA, sumqA, stat0, red);
}

// ---------------------------------------------------------------------------
// Stage 1 (heavy-first): hd1(0..4) MT14, fd1(5,6) MT15, hf1(7,8), phu1(9,10),
//                        phl1(11,12) register
// ---------------------------------------------------------------------------
__global__ void __launch_bounds__(256, 3) stage1_kernel(
    const float* __restrict__ xp, const float* __restrict__ xh,
    const float* __restrict__ xf, const float* __restrict__ p_fea,
    const float* __restrict__ h_fea,
    const float* __restrict__ w_hf1, const float* __restrict__ w_fd1,
    const float* __restrict__ w_phu1, const float* __restrict__ w_phl1,
    const float* __restrict__ w_hd1, float* __restrict__ ws)
{
    __shared__ __align__(16) float stagebuf[4 * 2048];   // 32KB: 4 waves x 2 bufs x 4KB
    __shared__ __align__(16) float wlds[15 * 268];       // max slice (fd1 MT15)
    __shared__ float red[4 * 15 * 2];
    int g = blockIdx.x * 256 + threadIdx.x;
    int p = g * 4;
    int b = (p >= HW) ? 1 : 0;
    int s = p - b * HW;
    float* y     = ws;
    float* sumA  = ws + (size_t)NSLOT * NPOS;
    float* sumqA = sumA + NSTAT;
    float* wstage = stagebuf + (threadIdx.x >> 6) * 2048;
    int lane4 = (threadIdx.x & 63) * 4;
    int yb = blockIdx.y;

    if (yb < 5) {            // hd1: [p_fea; xh1; xh2] (276), MT14, 69 chunks
        int off = yb * 14;
        stage_w<276, 276, 14>(w_hd1 + off * 276, wlds);
        const float* pb = p_fea + (size_t)b * 256 * HW + s;
        const float* xb = xh + ((size_t)b * 30 + 10) * HW + s;
        float4 acc[14];
#pragma unroll
        for (int o = 0; o < 14; ++o) acc[o] = make_float4(0.f, 0.f, 0.f, 0.f);
        auto gp = [&](int j) -> const float* {
            return (j < 256) ? pb + (size_t)j * HW : xb + (size_t)(j - 256) * HW; };
        pipe4<69>(wstage, gp, [&](int k, float* bb) {
            float4 xs[4];
#pragma unroll
            for (int i = 0; i < 4; ++i) xs[i] = *(float4*)(bb + i * 256 + lane4);
#pragma unroll
            for (int o = 0; o < 14; ++o)
                fma4x4(acc[o], ld4(wlds + o * 276 + k * 4), xs);
        });
        finish<14>(acc, y + (size_t)(S1_HD1 + off) * NPOS, p, sumA, sumqA, S1_HD1 + off, red);
    } else if (yb < 7) {     // fd1: [h_fea; xf1] (266), MT15: 66 chunks + 2 reg tail
        int off = (yb - 5) * 15;
        stage_w<266, 268, 15>(w_fd1 + off * 266, wlds);
        const float* hb  = h_fea + (size_t)b * 256 * HW + s;
        const float* xf1 = xf + ((size_t)b * 20 + 10) * HW + s;
        float4 acc[15];
#pragma unroll
        for (int o = 0; o < 15; ++o) acc[o] = make_float4(0.f, 0.f, 0.f, 0.f);
        auto gp = [&](int j) -> const float* {
            return (j < 256) ? hb + (size_t)j * HW : xf1 + (size_t)(j - 256) * HW; };
        pipe4<66>(wstage, gp, [&](int k, float* bb) {
            float4 xs[4];
#pragma unroll
            for (int i = 0; i < 4; ++i) xs[i] = *(float4*)(bb + i * 256 + lane4);
#pragma unroll
            for (int o = 0; o < 15; ++o)
                fma4x4(acc[o], ld4(wlds + o * 268 + k * 4), xs);
        });
        float4 t0 = ld4(xf1 + (size_t)8 * HW);
        float4 t1 = ld4(xf1 + (size_t)9 * HW);
#pragma unroll
        for (int o = 0; o < 15; ++o) {
            fma1(acc[o], wlds[o * 268 + 264], t0);
            fma1(acc[o], wlds[o * 268 + 265], t1);
        }
        finish<15>(acc, y + (size_t)(S1_FD1 + off) * NPOS, p, sumA, sumqA, S1_FD1 + off, red);
    } else if (yb < 9) {     // hf1 (20) register path
        int off = (yb - 7) * 10;
        stage_w<20, 20, 10>(w_hf1 + off * 20, wlds);
        const float* xb = xh + ((size_t)b * 30 + 10) * HW + s;
        conv4s<20, 20, 10>([&](int c) { return ld4(xb + c * HW); },
                       wlds, y + (size_t)(S1_HF1 + off) * NPOS, p,
                       sumA, sumqA, S1_HF1 + off, red);
    } else if (yb < 11) {    // phu1 (40) register path
        int off = (yb - 9) * 10;
        stage_w<40, 40, 10>(w_phu1 + off * 40, wlds);
        const float* xb = xp + ((size_t)b * 70 + 10) * HW + s;
        conv4s<40, 40, 10>([&](int c) { return ld4(xb + c * HW); },
                       wlds, y + (size_t)(S1_PHU1 + off) * NPOS, p,
                       sumA, sumqA, S1_PHU1 + off, red);
    } else {                 // phl1 (20) register path
        int off = (yb - 11) * 10;
        stage_w<20, 20, 10>(w_phl1 + off * 20, wlds);
        const float* xb = xp + ((size_t)b * 70 + 50) * HW + s;
        conv4s<20, 20, 10>([&](int c) { return ld4(xb + c * HW); },
                       wlds, y + (size_t)(S1_PHL1 + off) * NPOS, p,
                       sumA, sumqA, S1_PHL1 + off, red);
    }
}

// ---------------------------------------------------------------------------
__global__ void scale_kernel(int stage,
    const float* __restrict__ bn_hf1, const float* __restrict__ bn_hf2,
    const float* __restrict__ bn_phu1, const float* __restrict__ bn_phu2,
    const float* __restrict__ bn_phl1, const float* __restrict__ bn_phl2,
    const float* __restrict__ bn_fd1, const float* __restrict__ bn_fd2,
    const float* __restrict__ bn_hd1, const float* __restrict__ bn_hd2,
    const float* __restrict__ bn_fu, const float* __restrict__ bn_hu,
    const float* __restrict__ bn_pu, float* __restrict__ ws)
{
    int t = threadIdx.x;
    float* sumA   = ws + (size_t)NSLOT * NPOS;
    float* sumqA  = sumA + NSTAT;
    float* scaleA = sumqA + NSTAT;
    float* shiftA = scaleA + NSTAT;
    int stat, local, co;
    const float* bn;
    if (stage == 1) {
        if (t >= 160) return;
        stat = t;
        if      (t < 20) { bn = bn_hf1;  local = t;      co = 20; }
        else if (t < 50) { bn = bn_fd1;  local = t - 20; co = 30; }
        else if (t < 70) { bn = bn_phu1; local = t - 50; co = 20; }
        else if (t < 90) { bn = bn_phl1; local = t - 70; co = 20; }
        else             { bn = bn_hd1;  local = t - 90; co = 70; }
    } else if (stage == 2) {
        if (t >= 130) return;
        stat = 160 + t;
        if      (t < 10) { bn = bn_hf2;  local = t;      co = 10; }
        else if (t < 40) { bn = bn_fd2;  local = t - 10; co = 30; }
        else if (t < 50) { bn = bn_phu2; local = t - 40; co = 10; }
        else if (t < 60) { bn = bn_phl2; local = t - 50; co = 10; }
        else             { bn = bn_hd2;  local = t - 60; co = 70; }
    } else {
        if (t >= 120) return;
        stat = 290 + t;
        if      (t < 20) { bn = bn_fu; local = t;      co = 20; }
        else if (t < 50) { bn = bn_hu; local = t - 20; co = 30; }
        else             { bn = bn_pu; local = t - 50; co = 70; }
    }
    float n  = (float)NPOS;
    float m  = sumA[stat] / n;
    float v  = sumqA[stat] / n - m * m;
    float g  = bn[local];
    float bt = bn[co + local];
    float sc = g * rsqrtf(v + EPSV);
    scaleA[stat] = sc;
    shiftA[stat] = bt - m * sc;
}

// ---------------------------------------------------------------------------
// Stage 2 (heavy-first): hd2(0..4) MT14 staged, fd2(5,6) MT15 reg,
//                        hf2(7)/phu2(8)/phl2(9) reg
// ---------------------------------------------------------------------------
__global__ void __launch_bounds__(256, 4) stage2_kernel(
    const float* __restrict__ w_hf2, const float* __restrict__ w_fd2,
    const float* __restrict__ w_phu2, const float* __restrict__ w_phl2,
    const float* __restrict__ w_hd2, float* __restrict__ ws)
{
    __shared__ __align__(16) float stagebuf[4 * 2048];
    __shared__ __align__(16) float wlds[14 * 72];
    __shared__ float red[4 * 15 * 2];
    __shared__ float ssc[160], ssh[160];
    int g = blockIdx.x * 256 + threadIdx.x;
    int p = g * 4;
    float* y     = ws;
    float* sumA  = ws + (size_t)NSLOT * NPOS;
    float* sumqA = sumA + NSTAT;
    const float* scaleA = sumqA + NSTAT;
    const float* shiftA = scaleA + NSTAT;
    float* wstage = stagebuf + (threadIdx.x >> 6) * 2048;
    int lane4 = (threadIdx.x & 63) * 4;

    for (int i = threadIdx.x; i < 160; i += 256) { ssc[i] = scaleA[i]; ssh[i] = shiftA[i]; }
    int yb = blockIdx.y;

    if (yb < 5) {            // hd2: hd1(70), MT14: 17 chunks + 2 reg tail
        int off = yb * 14;
        stage_w<70, 72, 14>(w_hd2 + off * 70, wlds);
        const float* src = y + (size_t)S1_HD1 * NPOS + p;
        float4 acc[14];
#pragma unroll
        for (int o = 0; o < 14; ++o) acc[o] = make_float4(0.f, 0.f, 0.f, 0.f);
        auto gp = [&](int j) -> const float* { return src + (size_t)j * NPOS; };
        pipe4<17>(wstage, gp, [&](int k, float* bb) {
            float4 xs[4];
#pragma unroll
            for (int i = 0; i < 4; ++i) {
                int c = k * 4 + i;
                float4 v = *(float4*)(bb + i * 256 + lane4);
                xs[i] = bnrelu4(v, ssc[S1_HD1 + c], ssh[S1_HD1 + c]);
            }
#pragma unroll
            for (int o = 0; o < 14; ++o)
                fma4x4(acc[o], ld4(wlds + o * 72 + k * 4), xs);
        });
        float4 t0 = bnrelu4(ld4(src + (size_t)68 * NPOS), ssc[S1_HD1 + 68], ssh[S1_HD1 + 68]);
        float4 t1 = bnrelu4(ld4(src + (size_t)69 * NPOS), ssc[S1_HD1 + 69], ssh[S1_HD1 + 69]);
#pragma unroll
        for (int o = 0; o < 14; ++o) {
            fma1(acc[o], wlds[o * 72 + 68], t0);
            fma1(acc[o], wlds[o * 72 + 69], t1);
        }
        finish<14>(acc, y + (size_t)(S2_HD2 + off) * NPOS, p, sumA, sumqA, S2_HD2 + off, red);
    } else if (yb < 7) {     // fd2 (30), MT15 register path
        int off = (yb - 5) * 15;
        stage_w<30, 32, 15>(w_fd2 + off * 30, wlds);
        const float* src = y + (size_t)S1_FD1 * NPOS + p;
        conv4s<30, 32, 15>([&](int c) {
            return bnrelu4(ld4(src + (size_t)c * NPOS), ssc[S1_FD1 + c], ssh[S1_FD1 + c]); },
            wlds, y + (size_t)(S2_FD2 + off) * NPOS, p, sumA, sumqA, S2_FD2 + off, red);
    } else if (yb == 7) {    // hf2
        stage_w<20, 20, 10>(w_hf2, wlds);
        const float* src = y + (size_t)S1_HF1 * NPOS + p;
        conv4s<20, 20, 10>([&](int c) {
            return bnrelu4(ld4(src + (size_t)c * NPOS), ssc[S1_HF1 + c], ssh[S1_HF1 + c]); },
            wlds, y + (size_t)S2_HF2 * NPOS, p, sumA, sumqA, S2_HF2, red);
    } else if (yb == 8) {    // phu2
        stage_w<20, 20, 10>(w_phu2, wlds);
        const float* src = y + (size_t)S1_PHU1 * NPOS + p;
        conv4s<20, 20, 10>([&](int c) {
            return bnrelu4(ld4(src + (size_t)c * NPOS), ssc[S1_PHU1 + c], ssh[S1_PHU1 + c]); },
            wlds, y + (size_t)S2_PHU2 * NPOS, p, sumA, sumqA, S2_PHU2, red);
    } else {                 // phl2
        stage_w<20, 20, 10>(w_phl2, wlds);
        const float* src = y + (size_t)S1_PHL1 * NPOS + p;
        conv4s<20, 20, 10>([&](int c) {
            return bnrelu4(ld4(src + (size_t)c * NPOS), ssc[S1_PHL1 + c], ssh[S1_PHL1 + c]); },
            wlds, y + (size_t)S2_PHL2 * NPOS, p, sumA, sumqA, S2_PHL2, red);
    }
}

// ---------------------------------------------------------------------------
// Stage 3 (heavy-first): pu(0..4) MT14, hu(5,6) MT15, fu(7,8) MT10 — staged.
// ---------------------------------------------------------------------------
__global__ void __launch_bounds__(256, 3) stage3_kernel(
    const float* __restrict__ xp, const float* __restrict__ xh,
    const float* __restrict__ xf, const float* __restrict__ p_fea,
    const float* __restrict__ h_fea, const float* __restrict__ f_fea,
    const float* __restrict__ w_fu, const float* __restrict__ w_hu,
    const float* __restrict__ w_pu, float* __restrict__ ws)
{
    __shared__ __align__(16) float stagebuf[4 * 2048];
    __shared__ __align__(16) float wlds[14 * 316];
    __shared__ float red[4 * 15 * 2];
    __shared__ float ssc[130], ssh[130];
    int g = blockIdx.x * 256 + threadIdx.x;
    int p = g * 4;
    int b = (p >= HW) ? 1 : 0;
    int s = p - b * HW;
    float* y     = ws;
    float* sumA  = ws + (size_t)NSLOT * NPOS;
    float* sumqA = sumA + NSTAT;
    const float* scaleA = sumqA + NSTAT;
    const float* shiftA = scaleA + NSTAT;
    float* wstage = stagebuf + (threadIdx.x >> 6) * 2048;
    int lane4 = (threadIdx.x & 63) * 4;

    for (int i = threadIdx.x; i < 130; i += 256) {
        ssc[i] = scaleA[L2OFF + i]; ssh[i] = shiftA[L2OFF + i];
    }
    int yb = blockIdx.y;

    if (yb < 5) {            // pu (316), MT14: 256 pure + 60 pairs = 94 chunks
        int off = yb * 14;
        stage_w<316, 316, 14>(w_pu + off * 316, wlds);
        const float* pb   = p_fea + (size_t)b * 256 * HW + s;
        const float* yhd2 = y + (size_t)S2_HD2 * NPOS + p;
        const float* xpb  = xp + ((size_t)b * 70 + 10) * HW + s;
        float4 acc[14];
#pragma unroll
        for (int o = 0; o < 14; ++o) acc[o] = make_float4(0.f, 0.f, 0.f, 0.f);
        auto gp = [&](int j) -> const float* {
            if (j < 256) return pb + (size_t)j * HW;
            int jj = j - 256, t = jj >> 1;
            return (jj & 1) ? xpb + (size_t)t * HW
                            : yhd2 + (size_t)(10 + t) * NPOS; };
        pipe4<94>(wstage, gp, [&](int k, float* bb) {
            if (k < 64) {
                float4 xs[4];
#pragma unroll
                for (int i = 0; i < 4; ++i) xs[i] = *(float4*)(bb + i * 256 + lane4);
#pragma unroll
                for (int o = 0; o < 14; ++o)
                    fma4x4(acc[o], ld4(wlds + o * 316 + k * 4), xs);
            } else {
                int t0 = (k - 64) * 2;          // 2 channels per chunk
                float4 x[2];
#pragma unroll
                for (int q = 0; q < 2; ++q) {
                    float4 a  = *(float4*)(bb + (2 * q) * 256 + lane4);
                    float4 bx = *(float4*)(bb + (2 * q + 1) * 256 + lane4);
                    int ia = S2_HD2 - L2OFF + 10 + t0 + q;
                    x[q] = add4(bnrelu4(a, ssc[ia], ssh[ia]), bx);
                }
                int c0 = 256 + t0;
#pragma unroll
                for (int o = 0; o < 14; ++o) {
                    float2 w2 = *(const float2*)(wlds + o * 316 + c0);
                    fma1(acc[o], w2.x, x[0]);
                    fma1(acc[o], w2.y, x[1]);
                }
            }
        });
        finish<14>(acc, y + (size_t)(S3_PU + off) * NPOS, p, sumA, sumqA, ST3_PU + off, red);
    } else if (yb < 7) {     // hu (276), MT15: 256 pure + 20 quads = 84 chunks
        int off = (yb - 5) * 15;
        stage_w<276, 276, 15>(w_hu + off * 276, wlds);
        const float* hb    = h_fea + (size_t)b * 256 * HW + s;
        const float* yphu2 = y + (size_t)S2_PHU2 * NPOS + p;
        const float* yphl2 = y + (size_t)S2_PHL2 * NPOS + p;
        const float* yfd2  = y + (size_t)S2_FD2 * NPOS + p;
        const float* xh1b  = xh + ((size_t)b * 30 + 10) * HW + s;
        float4 acc[15];
#pragma unroll
        for (int o = 0; o < 15; ++o) acc[o] = make_float4(0.f, 0.f, 0.f, 0.f);
        auto gp = [&](int j) -> const float* {
            if (j < 256) return hb + (size_t)j * HW;
            int jj = j - 256, t = jj >> 2, r = jj & 3;
            if (r == 0) return (t < 10) ? yphu2 + (size_t)t * NPOS
                                        : yphl2 + (size_t)(t - 10) * NPOS;
            if (r == 1) return yfd2 + (size_t)(10 + t) * NPOS;
            return xh1b + (size_t)t * HW;      // r==2 real, r==3 pad
        };
        pipe4<84>(wstage, gp, [&](int k, float* bb) {
            if (k < 64) {
                float4 xs[4];
#pragma unroll
                for (int i = 0; i < 4; ++i) xs[i] = *(float4*)(bb + i * 256 + lane4);
#pragma unroll
                for (int o = 0; o < 15; ++o)
                    fma4x4(acc[o], ld4(wlds + o * 276 + k * 4), xs);
            } else {
                int t = k - 64;                 // 1 channel per chunk
                float4 A = *(float4*)(bb + 0 * 256 + lane4);
                float4 F = *(float4*)(bb + 1 * 256 + lane4);
                float4 R = *(float4*)(bb + 2 * 256 + lane4);
                int ia = (t < 10) ? (S2_PHU2 - L2OFF + t) : (S2_PHL2 - L2OFF + t - 10);
                int iff = S2_FD2 - L2OFF + 10 + t;
                float4 a = bnrelu4(A, ssc[ia], ssh[ia]);
                float4 f = bnrelu4(F, ssc[iff], ssh[iff]);
                float4 x = make_float4(R.x + a.x + f.x, R.y + a.y + f.y,
                                       R.z + a.z + f.z, R.w + a.w + f.w);
                int c = 256 + t;
#pragma unroll
                for (int o = 0; o < 15; ++o)
                    fma1(acc[o], wlds[o * 276 + c], x);
            }
        });
        finish<15>(acc, y + (size_t)(S3_HU + off) * NPOS, p, sumA, sumqA, ST3_HU + off, red);
    } else {                 // fu (266), MT10: 256 pure + 10 pairs = 69 chunks
        int off = (yb - 7) * 10;
        stage_w<266, 268, 10>(w_fu + off * 266, wlds);
        const float* fb   = f_fea + (size_t)b * 256 * HW + s;
        const float* yhf2 = y + (size_t)S2_HF2 * NPOS + p;
        const float* xf1  = xf + ((size_t)b * 20 + 10) * HW + s;
        float4 acc[10];
#pragma unroll
        for (int o = 0; o < 10; ++o) acc[o] = make_float4(0.f, 0.f, 0.f, 0.f);
        auto gp = [&](int j) -> const float* {
            if (j < 256) return fb + (size_t)j * HW;
            int jj = j - 256, t = jj >> 1;
            return (jj & 1) ? xf1 + (size_t)t * HW
                            : yhf2 + (size_t)t * NPOS; };
        pipe4<69>(wstage, gp, [&](int k, float* bb) {
            if (k < 64) {
                float4 xs[4];
#pragma unroll
                for (int i = 0; i < 4; ++i) xs[i] = *(float4*)(bb + i * 256 + lane4);
#pragma unroll
                for (int o = 0; o < 10; ++o)
                    fma4x4(acc[o], ld4(wlds + o * 268 + k * 4), xs);
            } else {
                int t0 = (k - 64) * 2;          // 2 channels per chunk
                float4 x[2];
#pragma unroll
                for (int q = 0; q < 2; ++q) {
                    float4 a  = *(float4*)(bb + (2 * q) * 256 + lane4);
                    float4 bx = *(float4*)(bb + (2 * q + 1) * 256 + lane4);
                    int i0 = S2_HF2 - L2OFF + t0 + q;
                    x[q] = add4(bnrelu4(a, ssc[i0], ssh[i0]), bx);
                }
                int c0 = 256 + t0;
#pragma unroll
                for (int o = 0; o < 10; ++o) {
                    float2 w2 = *(const float2*)(wlds + o * 268 + c0);
                    fma1(acc[o], w2.x, x[0]);
                    fma1(acc[o], w2.y, x[1]);
                }
            }
        });
        finish<10>(acc, y + (size_t)(S3_FU + off) * NPOS, p, sumA, sumqA, ST3_FU + off, red);
    }
}

// ---------------------------------------------------------------------------
__global__ void __launch_bounds__(256) final_kernel(const float* __restrict__ ws,
                                                    float* __restrict__ out)
{
    int g = blockIdx.x * 256 + threadIdx.x;
    int p = g * 4;
    int c = blockIdx.y;
    const float* sumA   = ws + (size_t)NSLOT * NPOS;
    const float* scaleA = sumA + 2 * NSTAT;
    const float* shiftA = scaleA + NSTAT;
    int slot, stat;
    if      (c < 70)  { slot = S3_PU  + c;         stat = ST3_PU  + c;         }
    else if (c < 100) { slot = S3_HU  + (c - 70);  stat = ST3_HU  + (c - 70);  }
    else if (c < 120) { slot = S3_FU  + (c - 100); stat = ST3_FU  + (c - 100); }
    else if (c < 150) { slot = S2_FD2 + (c - 120); stat = S2_FD2 + (c - 120);  }
    else              { slot = S2_HD2 + (c - 150); stat = S2_HD2 + (c - 150);  }
    float4 v = *(const float4*)(ws + (size_t)slot * NPOS + p);
    float sc = scaleA[stat], sh = shiftA[stat];
    v.x = fmaf(v.x, sc, sh); v.x = v.x > 0.f ? v.x : 0.f;
    v.y = fmaf(v.y, sc, sh); v.y = v.y > 0.f ? v.y : 0.f;
    v.z = fmaf(v.z, sc, sh); v.z = v.z > 0.f ? v.z : 0.f;
    v.w = fmaf(v.w, sc, sh); v.w = v.w > 0.f ? v.w : 0.f;
    int b = (p >= HW) ? 1 : 0;
    int s = p - b * HW;
    *(float4*)(out + ((size_t)b * 220 + c) * HW + s) = v;
}

// ---------------------------------------------------------------------------
extern "C" void kernel_launch(void* const* d_in, const int* in_sizes, int n_in,
                              void* d_out, int out_size, void* d_ws, size_t ws_size,
                              hipStream_t stream)
{
    const float* xp     = (const float*)d_in[0];
    const float* xh     = (const float*)d_in[1];
    const float* xf     = (const float*)d_in[2];
    const float* p_fea  = (const float*)d_in[3];
    const float* h_fea  = (const float*)d_in[4];
    const float* f_fea  = (const float*)d_in[5];
    const float* w_hf1  = (const float*)d_in[6];  const float* bn_hf1  = (const float*)d_in[7];
    const float* w_hf2  = (const float*)d_in[8];  const float* bn_hf2  = (const float*)d_in[9];
    const float* w_phu1 = (const float*)d_in[10]; const float* bn_phu1 = (const float*)d_in[11];
    const float* w_phu2 = (const float*)d_in[12]; const float* bn_phu2 = (const float*)d_in[13];
    const float* w_phl1 = (const float*)d_in[14]; const float* bn_phl1 = (const float*)d_in[15];
    const float* w_phl2 = (const float*)d_in[16]; const float* bn_phl2 = (const float*)d_in[17];
    const float* w_fd1  = (const float*)d_in[18]; const float* bn_fd1  = (const float*)d_in[19];
    const float* w_fd2  = (const float*)d_in[20]; const float* bn_fd2  = (const float*)d_in[21];
    const float* w_hd1  = (const float*)d_in[22]; const float* bn_hd1  = (const float*)d_in[23];
    const float* w_hd2  = (const float*)d_in[24]; const float* bn_hd2  = (const float*)d_in[25];
    const float* w_fu   = (const float*)d_in[26]; const float* bn_fu   = (const float*)d_in[27];
    const float* w_hu   = (const float*)d_in[28]; const float* bn_hu   = (const float*)d_in[29];
    const float* w_pu   = (const float*)d_in[30]; const float* bn_pu   = (const float*)d_in[31];

    float* ws  = (float*)d_ws;
    float* out = (float*)d_out;

    size_t need_bytes = ((size_t)NSLOT * NPOS + 4 * NSTAT) * sizeof(float);
    if (ws_size < need_bytes) return;

    hipMemsetAsync(ws + (size_t)NSLOT * NPOS, 0, 2 * NSTAT * sizeof(float), stream);

    dim3 blk(256);
    const int GX = NPOS / 1024;   // 72 x-blocks, 4 positions/thread
    stage1_kernel<<<dim3(GX, 13), blk, 0, stream>>>(xp, xh, xf, p_fea, h_fea,
                                                    w_hf1, w_fd1, w_phu1, w_phl1, w_hd1, ws);
    scale_kernel<<<1, 256, 0, stream>>>(1, bn_hf1, bn_hf2, bn_phu1, bn_phu2, bn_phl1, bn_phl2,
                                        bn_fd1, bn_fd2, bn_hd1, bn_hd2, bn_fu, bn_hu, bn_pu, ws);
    stage2_kernel<<<dim3(GX, 10), blk, 0, stream>>>(w_hf2, w_fd2, w_phu2, w_phl2, w_hd2, ws);
    scale_kernel<<<1, 256, 0, stream>>>(2, bn_hf1, bn_hf2, bn_phu1, bn_phu2, bn_phl1, bn_phl2,
                                        bn_fd1, bn_fd2, bn_hd1, bn_hd2, bn_fu, bn_hu, bn_pu, ws);
    stage3_kernel<<<dim3(GX, 9), blk, 0, stream>>>(xp, xh, xf, p_fea, h_fea, f_fea,
                                                   w_fu, w_hu, w_pu, ws);
    scale_kernel<<<1, 256, 0, stream>>>(3, bn_hf1, bn_hf2, bn_phu1, bn_phu2, bn_phl1, bn_phl2,
                                        bn_fd1, bn_fd2, bn_hd1, bn_hd2, bn_fu, bn_hu, bn_pu, ws);
    final_kernel<<<dim3(NPOS / 1024, 220), blk, 0, stream>>>(ws, out);
}